// Round 2
// baseline (498.145 us; speedup 1.0000x reference)
//
#include <hip/hip_runtime.h>
#include <stdint.h>

#define DEV __device__ __forceinline__

typedef unsigned short u16;
typedef __bf16 bf16x8 __attribute__((ext_vector_type(8)));
typedef float f32x4 __attribute__((ext_vector_type(4)));
typedef u16 u16x8 __attribute__((ext_vector_type(8)));

#define MFMA_BF16(A, B, C) __builtin_amdgcn_mfma_f32_16x16x32_bf16(A, B, C, 0, 0, 0)

DEV u16 f2bf(float f) {
    unsigned x;
    __builtin_memcpy(&x, &f, 4);
    unsigned r = (x + 0x7fffu + ((x >> 16) & 1u)) >> 16;  // RNE
    return (u16)r;
}

DEV void storeC(u16* p, float v) { *p = f2bf(v); }
DEV void storeC(float* p, float v) { *p = v; }

// async global->LDS, 16B per lane. LDS dest must be wave-uniform base + lane*16.
DEV void async_copy16(const u16* g, u16* l) {
    __builtin_amdgcn_global_load_lds(
        (__attribute__((address_space(1))) unsigned int*)g,
        (__attribute__((address_space(3))) unsigned int*)l, 16, 0, 0);
}

// ---------------------------------------------------------------------------
// fp32 -> bf16 conversion, 4 elems/thread. n must be a multiple of 1024.
// ---------------------------------------------------------------------------
__global__ __launch_bounds__(256)
void cvt_f32_bf16(const float* __restrict__ in, u16* __restrict__ out, int n) {
    const int i = (blockIdx.x * 256 + threadIdx.x) * 4;
    if (i < n) {
        const float4 v = *(const float4*)(in + i);
        ushort4 o;
        o.x = f2bf(v.x);
        o.y = f2bf(v.y);
        o.z = f2bf(v.z);
        o.w = f2bf(v.w);
        *(ushort4*)(out + i) = o;
    }
}

// ---------------------------------------------------------------------------
// C[M,N] = A[M,K] * Bw[N,K]^T + bias[N]; A,Bw bf16, bias fp32, fp32 accum.
// 128x128 tile, BK=32, 4 waves in 2x2, each wave 64x64 via 4x4 MFMA 16x16x32.
// ---------------------------------------------------------------------------
template <typename OT>
__global__ __launch_bounds__(256, 2)
void gemm_bt_bias(const u16* __restrict__ A, const u16* __restrict__ Bw,
                  const float* __restrict__ bias, OT* __restrict__ C,
                  int M, int N, int K) {
    __shared__ __attribute__((aligned(16))) u16 sA[128 * 32];
    __shared__ __attribute__((aligned(16))) u16 sB[128 * 32];

    const int tid  = threadIdx.x;
    const int lane = tid & 63;
    const int wave = tid >> 6;
    const int m0 = blockIdx.y * 128;
    const int n0 = blockIdx.x * 128;
    const int wm = (wave & 1) * 64;
    const int wn = (wave >> 1) * 64;
    const int fr = lane & 15;
    const int q4 = lane >> 4;

    const int r0 = tid >> 2;
    const int c0 = (tid & 3) * 8;
    const u16* gA0 = A + (size_t)(m0 + r0) * K + c0;
    const u16* gA1 = A + (size_t)(m0 + 64 + r0) * K + c0;
    const u16* gB0 = Bw + (size_t)(n0 + r0) * K + c0;
    const u16* gB1 = Bw + (size_t)(n0 + 64 + r0) * K + c0;
    u16* lA0 = &sA[tid * 8];
    u16* lA1 = &sA[2048 + tid * 8];
    u16* lB0 = &sB[tid * 8];
    u16* lB1 = &sB[2048 + tid * 8];

    f32x4 acc[4][4];
#pragma unroll
    for (int i = 0; i < 4; i++)
#pragma unroll
        for (int j = 0; j < 4; j++) acc[i][j] = (f32x4){0.f, 0.f, 0.f, 0.f};

    for (int k0 = 0; k0 < K; k0 += 32) {
        async_copy16(gA0 + k0, lA0);
        async_copy16(gA1 + k0, lA1);
        async_copy16(gB0 + k0, lB0);
        async_copy16(gB1 + k0, lB1);
        __syncthreads();

        bf16x8 af[4], bfr[4];
#pragma unroll
        for (int i = 0; i < 4; i++)
            af[i] = *(const bf16x8*)&sA[(wm + i * 16 + fr) * 32 + q4 * 8];
#pragma unroll
        for (int j = 0; j < 4; j++)
            bfr[j] = *(const bf16x8*)&sB[(wn + j * 16 + fr) * 32 + q4 * 8];
#pragma unroll
        for (int i = 0; i < 4; i++)
#pragma unroll
            for (int j = 0; j < 4; j++)
                acc[i][j] = MFMA_BF16(af[i], bfr[j], acc[i][j]);
        __syncthreads();
    }

    // epilogue: C/D layout col=lane&15, row=quad*4+reg  [verified m89/m91]
#pragma unroll
    for (int j = 0; j < 4; j++) {
        const int col = n0 + wn + j * 16 + fr;
        const float bv = bias[col];
#pragma unroll
        for (int i = 0; i < 4; i++) {
            const int row = m0 + wm + i * 16 + q4 * 4;
#pragma unroll
            for (int r = 0; r < 4; r++)
                storeC(&C[(size_t)(row + r) * N + col], acc[i][j][r] + bv);
        }
    }
}

// ---------------------------------------------------------------------------
// Flash attention, causal. qkv layout [B, L, 3, H, 64] bf16. One block per
// (b, h, 64-row Q tile); 4 waves each own 16 Q rows.
// ---------------------------------------------------------------------------
constexpr int Lc = 2048, Dc = 1024;

__global__ __launch_bounds__(256, 2)
void attn_fa(const u16* __restrict__ qkv, u16* __restrict__ outb) {
    __shared__ __attribute__((aligned(16))) u16 sK[64 * 72];     // [j][d] pad 72
    __shared__ __attribute__((aligned(16))) u16 sVT[64 * 72];    // [d][j] pad 72
    __shared__ __attribute__((aligned(16))) u16 sP[4][16 * 72];  // per-wave [i][j]

    const int tid  = threadIdx.x;
    const int lane = tid & 63;
    const int wave = tid >> 6;
    const int fr = lane & 15;
    const int q4 = lane >> 4;
    const int qblk = blockIdx.x;
    const int h = blockIdx.y;
    const int b = blockIdx.z;

    // Q fragments (A-operand: m=lane&15, k=quad*8+j  [m120])
    const int qrow = qblk * 64 + wave * 16 + fr;
    const u16* qptr = qkv + ((size_t)(b * Lc + qrow) * 3) * Dc + h * 64;
    bf16x8 qf[2];
    qf[0] = *(const bf16x8*)(qptr + q4 * 8);
    qf[1] = *(const bf16x8*)(qptr + 32 + q4 * 8);

    f32x4 o_acc[4];
#pragma unroll
    for (int t = 0; t < 4; t++) o_acc[t] = (f32x4){0.f, 0.f, 0.f, 0.f};
    float m_i[4], l_i[4];
#pragma unroll
    for (int r = 0; r < 4; r++) { m_i[r] = -3.4e38f; l_i[r] = 0.f; }

    const int i_g = qblk * 64 + wave * 16 + q4 * 4;  // + r

    for (int jb = 0; jb <= qblk; ++jb) {
        // stage K tile and transposed V tile
#pragma unroll
        for (int c2 = 0; c2 < 2; ++c2) {
            const int c = c2 * 256 + tid;
            const int j = c >> 3;
            const int o = c & 7;
            const size_t rowbase = ((size_t)(b * Lc + jb * 64 + j) * 3) * Dc + h * 64 + o * 8;
            u16x8 kv = *(const u16x8*)(qkv + rowbase + Dc);       // K row j
            u16x8 vv = *(const u16x8*)(qkv + rowbase + 2 * Dc);   // V row j
            *(u16x8*)&sK[j * 72 + o * 8] = kv;
#pragma unroll
            for (int e = 0; e < 8; e++) sVT[(o * 8 + e) * 72 + j] = vv[e];
        }
        __syncthreads();

        // S = Q K^T (B-frag from sK rows: n=lane&15 -> key, contiguous d)
        f32x4 s[4];
#pragma unroll
        for (int t = 0; t < 4; t++) {
            s[t] = (f32x4){0.f, 0.f, 0.f, 0.f};
            s[t] = MFMA_BF16(qf[0], *(const bf16x8*)&sK[(t * 16 + fr) * 72 + q4 * 8], s[t]);
            s[t] = MFMA_BF16(qf[1], *(const bf16x8*)&sK[(t * 16 + fr) * 72 + 32 + q4 * 8], s[t]);
        }

        // scale + causal mask (C-layout: row=q4*4+r, col=fr)
#pragma unroll
        for (int t = 0; t < 4; t++) {
            const int jg = jb * 64 + t * 16 + fr;
#pragma unroll
            for (int r = 0; r < 4; r++) {
                float v = s[t][r] * 0.125f;
                s[t][r] = (jg > i_g + r) ? -1e30f : v;
            }
        }

        // online softmax: row reductions live in one 16-lane quad (xor 1,2,4,8)
        float mnew[4], alpha[4];
#pragma unroll
        for (int r = 0; r < 4; r++) {
            float v = fmaxf(fmaxf(s[0][r], s[1][r]), fmaxf(s[2][r], s[3][r]));
            v = fmaxf(v, __shfl_xor(v, 1));
            v = fmaxf(v, __shfl_xor(v, 2));
            v = fmaxf(v, __shfl_xor(v, 4));
            v = fmaxf(v, __shfl_xor(v, 8));
            mnew[r] = fmaxf(m_i[r], v);
            alpha[r] = __expf(m_i[r] - mnew[r]);
        }

#pragma unroll
        for (int r = 0; r < 4; r++) {
            float sum = 0.f;
#pragma unroll
            for (int t = 0; t < 4; t++) {
                float p = __expf(s[t][r] - mnew[r]);
                sum += p;
                sP[wave][(q4 * 4 + r) * 72 + t * 16 + fr] = f2bf(p);
            }
            sum += __shfl_xor(sum, 1);
            sum += __shfl_xor(sum, 2);
            sum += __shfl_xor(sum, 4);
            sum += __shfl_xor(sum, 8);
            l_i[r] = alpha[r] * l_i[r] + sum;
            m_i[r] = mnew[r];
#pragma unroll
            for (int t = 0; t < 4; t++) o_acc[t][r] *= alpha[r];
        }

        // O += P V   (A-frag = P rows; B-frag = V^T rows, contiguous j)
#pragma unroll
        for (int ks = 0; ks < 2; ++ks) {
            bf16x8 pf = *(const bf16x8*)&sP[wave][fr * 72 + ks * 32 + q4 * 8];
#pragma unroll
            for (int t = 0; t < 4; t++) {
                bf16x8 vf = *(const bf16x8*)&sVT[(t * 16 + fr) * 72 + ks * 32 + q4 * 8];
                o_acc[t] = MFMA_BF16(pf, vf, o_acc[t]);
            }
        }
        __syncthreads();
    }

    // epilogue: O /= l, write [B, L, H*64] bf16
#pragma unroll
    for (int t = 0; t < 4; t++) {
        const int d = h * 64 + t * 16 + fr;
#pragma unroll
        for (int r = 0; r < 4; r++) {
            const float v = o_acc[t][r] / l_i[r];
            outb[(size_t)(b * Lc + i_g + r) * Dc + d] = f2bf(v);
        }
    }
}

// ---------------------------------------------------------------------------
extern "C" void kernel_launch(void* const* d_in, const int* in_sizes, int n_in,
                              void* d_out, int out_size, void* d_ws, size_t ws_size,
                              hipStream_t stream) {
    const float* x    = (const float*)d_in[0];  // [4,2048,1024] fp32
    const float* wqkv = (const float*)d_in[1];  // [3072,1024]
    const float* bqkv = (const float*)d_in[2];  // [3072]
    const float* wout = (const float*)d_in[3];  // [1024,1024]
    const float* bout = (const float*)d_in[4];  // [1024]
    float* out = (float*)d_out;                 // [4,2048,1024] fp32

    u16* qkv    = (u16*)d_ws;                       // [8192,3072] bf16
    u16* attn   = qkv + (size_t)8192 * 3072;        // [8192,1024] bf16
    u16* xbf    = attn + (size_t)8192 * 1024;       // [8192,1024] bf16
    u16* wqkvbf = xbf + (size_t)8192 * 1024;        // [3072,1024] bf16
    u16* woutbf = wqkvbf + (size_t)3072 * 1024;     // [1024,1024] bf16

    dim3 blk(256);
    cvt_f32_bf16<<<8192 * 1024 / 1024, blk, 0, stream>>>(x, xbf, 8192 * 1024);
    cvt_f32_bf16<<<3072 * 1024 / 1024, blk, 0, stream>>>(wqkv, wqkvbf, 3072 * 1024);
    cvt_f32_bf16<<<1024 * 1024 / 1024, blk, 0, stream>>>(wout, woutbf, 1024 * 1024);

    gemm_bt_bias<u16><<<dim3(3072 / 128, 8192 / 128), blk, 0, stream>>>(
        xbf, wqkvbf, bqkv, qkv, 8192, 3072, 1024);
    attn_fa<<<dim3(32, 16, 4), blk, 0, stream>>>(qkv, attn);
    gemm_bt_bias<float><<<dim3(1024 / 128, 8192 / 128), blk, 0, stream>>>(
        attn, woutbf, bout, out, 8192, 1024, 1024);
}

// Round 3
// 412.512 us; speedup vs baseline: 1.2076x; 1.2076x over previous
//
#include <hip/hip_runtime.h>
#include <stdint.h>

#define DEV __device__ __forceinline__

typedef unsigned short u16;
typedef __bf16 bf16x8 __attribute__((ext_vector_type(8)));
typedef float f32x4 __attribute__((ext_vector_type(4)));
typedef u16 u16x8 __attribute__((ext_vector_type(8)));

#define MFMA_BF16(A, B, C) __builtin_amdgcn_mfma_f32_16x16x32_bf16(A, B, C, 0, 0, 0)

DEV u16 f2bf(float f) {
    unsigned x;
    __builtin_memcpy(&x, &f, 4);
    unsigned r = (x + 0x7fffu + ((x >> 16) & 1u)) >> 16;  // RNE
    return (u16)r;
}

DEV void storeC(u16* p, float v) { *p = f2bf(v); }
DEV void storeC(float* p, float v) { *p = v; }

// async global->LDS, 16B per lane. LDS dest must be wave-uniform base + lane*16.
DEV void async_copy16(const u16* g, u16* l) {
    __builtin_amdgcn_global_load_lds(
        (__attribute__((address_space(1))) unsigned int*)g,
        (__attribute__((address_space(3))) unsigned int*)l, 16, 0, 0);
}

// ---------------------------------------------------------------------------
// fp32 -> bf16 conversion, 4 elems/thread.
// ---------------------------------------------------------------------------
__global__ __launch_bounds__(256)
void cvt_f32_bf16(const float* __restrict__ in, u16* __restrict__ out, int n) {
    const int i = (blockIdx.x * 256 + threadIdx.x) * 4;
    if (i < n) {
        const float4 v = *(const float4*)(in + i);
        ushort4 o;
        o.x = f2bf(v.x);
        o.y = f2bf(v.y);
        o.z = f2bf(v.z);
        o.w = f2bf(v.w);
        *(ushort4*)(out + i) = o;
    }
}

// ---------------------------------------------------------------------------
// C[M,N] = A[M,K] * Bw[N,K]^T + bias[N]; A,Bw bf16, bias fp32, fp32 accum.
// 128x128 tile, BK=32, 4 waves 2x2, each wave 64x64 via 4x4 MFMA 16x16x32.
// VSPLIT: cols >= 2048 (the V third of QKV) are stored TRANSPOSED into
// vT[col-2048][M] as packed ushort4 (4 consecutive tokens), not into C.
// ---------------------------------------------------------------------------
template <typename OT, bool VSPLIT>
__global__ __launch_bounds__(256, 2)
void gemm_bt_bias(const u16* __restrict__ A, const u16* __restrict__ Bw,
                  const float* __restrict__ bias, OT* __restrict__ C,
                  u16* __restrict__ vT, int M, int N, int K) {
    __shared__ __attribute__((aligned(16))) u16 sA[128 * 32];
    __shared__ __attribute__((aligned(16))) u16 sB[128 * 32];

    const int tid  = threadIdx.x;
    const int lane = tid & 63;
    const int wave = tid >> 6;
    const int m0 = blockIdx.y * 128;
    const int n0 = blockIdx.x * 128;
    const int wm = (wave & 1) * 64;
    const int wn = (wave >> 1) * 64;
    const int fr = lane & 15;
    const int q4 = lane >> 4;

    const int r0 = tid >> 2;
    const int c0 = (tid & 3) * 8;
    const u16* gA0 = A + (size_t)(m0 + r0) * K + c0;
    const u16* gA1 = A + (size_t)(m0 + 64 + r0) * K + c0;
    const u16* gB0 = Bw + (size_t)(n0 + r0) * K + c0;
    const u16* gB1 = Bw + (size_t)(n0 + 64 + r0) * K + c0;
    u16* lA0 = &sA[tid * 8];
    u16* lA1 = &sA[2048 + tid * 8];
    u16* lB0 = &sB[tid * 8];
    u16* lB1 = &sB[2048 + tid * 8];

    f32x4 acc[4][4];
#pragma unroll
    for (int i = 0; i < 4; i++)
#pragma unroll
        for (int j = 0; j < 4; j++) acc[i][j] = (f32x4){0.f, 0.f, 0.f, 0.f};

    for (int k0 = 0; k0 < K; k0 += 32) {
        async_copy16(gA0 + k0, lA0);
        async_copy16(gA1 + k0, lA1);
        async_copy16(gB0 + k0, lB0);
        async_copy16(gB1 + k0, lB1);
        __syncthreads();

        bf16x8 af[4], bfr[4];
#pragma unroll
        for (int i = 0; i < 4; i++)
            af[i] = *(const bf16x8*)&sA[(wm + i * 16 + fr) * 32 + q4 * 8];
#pragma unroll
        for (int j = 0; j < 4; j++)
            bfr[j] = *(const bf16x8*)&sB[(wn + j * 16 + fr) * 32 + q4 * 8];
#pragma unroll
        for (int i = 0; i < 4; i++)
#pragma unroll
            for (int j = 0; j < 4; j++)
                acc[i][j] = MFMA_BF16(af[i], bfr[j], acc[i][j]);
        __syncthreads();
    }

    // epilogue: C/D layout col=lane&15, row=quad*4+reg  [verified m89/m91]
#pragma unroll
    for (int j = 0; j < 4; j++) {
        const int col = n0 + wn + j * 16 + fr;
        const float bv = bias[col];
        if (VSPLIT && col >= 2048) {  // wave-uniform: col/16 uniform across fr
#pragma unroll
            for (int i = 0; i < 4; i++) {
                const int row = m0 + wm + i * 16 + q4 * 4;
                ushort4 o;
                o.x = f2bf(acc[i][j][0] + bv);
                o.y = f2bf(acc[i][j][1] + bv);
                o.z = f2bf(acc[i][j][2] + bv);
                o.w = f2bf(acc[i][j][3] + bv);
                *(ushort4*)&vT[(size_t)(col - 2048) * 8192 + row] = o;
            }
        } else {
#pragma unroll
            for (int i = 0; i < 4; i++) {
                const int row = m0 + wm + i * 16 + q4 * 4;
#pragma unroll
                for (int r = 0; r < 4; r++)
                    storeC(&C[(size_t)(row + r) * N + col], acc[i][j][r] + bv);
            }
        }
    }
}

// ---------------------------------------------------------------------------
// Flash attention, causal. Q,K from qkv [B, L, 3, H, 64]; V from vT [H*64, B*L]
// (pre-transposed by the QKV GEMM). One block per (b, h, 64-row Q tile);
// 4 waves each own 16 Q rows. qblk reversed so longest blocks dispatch first.
// ---------------------------------------------------------------------------
constexpr int Lc = 2048, Dc = 1024;

__global__ __launch_bounds__(256, 4)
void attn_fa(const u16* __restrict__ qkv, const u16* __restrict__ vT,
             u16* __restrict__ outb) {
    __shared__ __attribute__((aligned(16))) u16 sK[64 * 72];     // [j][d] pad 72
    __shared__ __attribute__((aligned(16))) u16 sVT[64 * 72];    // [d][j] pad 72
    __shared__ __attribute__((aligned(16))) u16 sP[4][16 * 72];  // per-wave [i][j]

    const int tid  = threadIdx.x;
    const int lane = tid & 63;
    const int wave = tid >> 6;
    const int fr = lane & 15;
    const int q4 = lane >> 4;
    const int qblk = 31 - blockIdx.x;  // longest blocks first
    const int h = blockIdx.y;
    const int b = blockIdx.z;

    // Q fragments (A-operand: m=lane&15, k=quad*8+j  [m120])
    const int qrow = qblk * 64 + wave * 16 + fr;
    const u16* qptr = qkv + ((size_t)(b * Lc + qrow) * 3) * Dc + h * 64;
    bf16x8 qf[2];
    qf[0] = *(const bf16x8*)(qptr + q4 * 8);
    qf[1] = *(const bf16x8*)(qptr + 32 + q4 * 8);

    f32x4 o_acc[4];
#pragma unroll
    for (int t = 0; t < 4; t++) o_acc[t] = (f32x4){0.f, 0.f, 0.f, 0.f};
    float m_i[4], l_i[4];
#pragma unroll
    for (int r = 0; r < 4; r++) { m_i[r] = -3.4e38f; l_i[r] = 0.f; }

    const int i_g = qblk * 64 + wave * 16 + q4 * 4;  // + r

    // staging pointers: rr = row (K) / d (vT), oo = 16B chunk
    const int rr = tid >> 3;      // first 32 rows; +32 on second pass
    const int oo = tid & 7;

    for (int jb = 0; jb <= qblk; ++jb) {
#pragma unroll
        for (int c2 = 0; c2 < 2; ++c2) {
            const int row = c2 * 32 + rr;
            *(u16x8*)&sK[row * 72 + oo * 8] =
                *(const u16x8*)(qkv + ((size_t)(b * Lc + jb * 64 + row) * 3) * Dc + Dc + h * 64 + oo * 8);
            *(u16x8*)&sVT[row * 72 + oo * 8] =
                *(const u16x8*)(vT + (size_t)(h * 64 + row) * 8192 + b * Lc + jb * 64 + oo * 8);
        }
        __syncthreads();

        // S = Q K^T (B-frag from sK rows: n=lane&15 -> key, contiguous d)
        f32x4 s[4];
#pragma unroll
        for (int t = 0; t < 4; t++) {
            s[t] = (f32x4){0.f, 0.f, 0.f, 0.f};
            s[t] = MFMA_BF16(qf[0], *(const bf16x8*)&sK[(t * 16 + fr) * 72 + q4 * 8], s[t]);
            s[t] = MFMA_BF16(qf[1], *(const bf16x8*)&sK[(t * 16 + fr) * 72 + 32 + q4 * 8], s[t]);
        }

        // scale; causal mask only on the diagonal tile (wave-uniform branch)
#pragma unroll
        for (int t = 0; t < 4; t++)
#pragma unroll
            for (int r = 0; r < 4; r++) s[t][r] *= 0.125f;
        if (jb == qblk) {
#pragma unroll
            for (int t = 0; t < 4; t++) {
                const int jg = jb * 64 + t * 16 + fr;
#pragma unroll
                for (int r = 0; r < 4; r++)
                    if (jg > i_g + r) s[t][r] = -1e30f;
            }
        }

        // online softmax: row reductions within one 16-lane quad
        float mnew[4], alpha[4];
#pragma unroll
        for (int r = 0; r < 4; r++) {
            float v = fmaxf(fmaxf(s[0][r], s[1][r]), fmaxf(s[2][r], s[3][r]));
            v = fmaxf(v, __shfl_xor(v, 1));
            v = fmaxf(v, __shfl_xor(v, 2));
            v = fmaxf(v, __shfl_xor(v, 4));
            v = fmaxf(v, __shfl_xor(v, 8));
            mnew[r] = fmaxf(m_i[r], v);
            alpha[r] = __expf(m_i[r] - mnew[r]);
        }

#pragma unroll
        for (int r = 0; r < 4; r++) {
            float sum = 0.f;
#pragma unroll
            for (int t = 0; t < 4; t++) {
                float p = __expf(s[t][r] - mnew[r]);
                sum += p;
                sP[wave][(q4 * 4 + r) * 72 + t * 16 + fr] = f2bf(p);
            }
            sum += __shfl_xor(sum, 1);
            sum += __shfl_xor(sum, 2);
            sum += __shfl_xor(sum, 4);
            sum += __shfl_xor(sum, 8);
            l_i[r] = alpha[r] * l_i[r] + sum;
            m_i[r] = mnew[r];
#pragma unroll
            for (int t = 0; t < 4; t++) o_acc[t][r] *= alpha[r];
        }

        // O += P V   (A-frag = P rows; B-frag = V^T rows, contiguous j)
#pragma unroll
        for (int ks = 0; ks < 2; ++ks) {
            bf16x8 pf = *(const bf16x8*)&sP[wave][fr * 72 + ks * 32 + q4 * 8];
#pragma unroll
            for (int t = 0; t < 4; t++) {
                bf16x8 vf = *(const bf16x8*)&sVT[(t * 16 + fr) * 72 + ks * 32 + q4 * 8];
                o_acc[t] = MFMA_BF16(pf, vf, o_acc[t]);
            }
        }
        __syncthreads();
    }

    // epilogue: O *= 1/l, write [B, L, H*64] bf16
    float rl[4];
#pragma unroll
    for (int r = 0; r < 4; r++) rl[r] = 1.0f / l_i[r];
#pragma unroll
    for (int t = 0; t < 4; t++) {
        const int d = h * 64 + t * 16 + fr;
#pragma unroll
        for (int r = 0; r < 4; r++)
            outb[(size_t)(b * Lc + i_g + r) * Dc + d] = f2bf(o_acc[t][r] * rl[r]);
    }
}

// ---------------------------------------------------------------------------
extern "C" void kernel_launch(void* const* d_in, const int* in_sizes, int n_in,
                              void* d_out, int out_size, void* d_ws, size_t ws_size,
                              hipStream_t stream) {
    const float* x    = (const float*)d_in[0];  // [4,2048,1024] fp32
    const float* wqkv = (const float*)d_in[1];  // [3072,1024]
    const float* bqkv = (const float*)d_in[2];  // [3072]
    const float* wout = (const float*)d_in[3];  // [1024,1024]
    const float* bout = (const float*)d_in[4];  // [1024]
    float* out = (float*)d_out;                 // [4,2048,1024] fp32

    u16* qkv    = (u16*)d_ws;                       // [8192,3072] bf16 (V third unused)
    u16* attn   = qkv + (size_t)8192 * 3072;        // [8192,1024] bf16
    u16* xbf    = attn + (size_t)8192 * 1024;       // [8192,1024] bf16
    u16* wqkvbf = xbf + (size_t)8192 * 1024;        // [3072,1024] bf16
    u16* woutbf = wqkvbf + (size_t)3072 * 1024;     // [1024,1024] bf16
    u16* vT     = woutbf + (size_t)1024 * 1024;     // [1024, 8192] bf16 (V transposed)

    dim3 blk(256);
    cvt_f32_bf16<<<8192 * 1024 / 1024, blk, 0, stream>>>(x, xbf, 8192 * 1024);
    cvt_f32_bf16<<<3072 * 1024 / 1024, blk, 0, stream>>>(wqkv, wqkvbf, 3072 * 1024);
    cvt_f32_bf16<<<1024 * 1024 / 1024, blk, 0, stream>>>(wout, woutbf, 1024 * 1024);

    gemm_bt_bias<u16, true><<<dim3(3072 / 128, 8192 / 128), blk, 0, stream>>>(
        xbf, wqkvbf, bqkv, qkv, vT, 8192, 3072, 1024);
    attn_fa<<<dim3(32, 16, 4), blk, 0, stream>>>(qkv, vT, attn);
    gemm_bt_bias<float, false><<<dim3(1024 / 128, 8192 / 128), blk, 0, stream>>>(
        attn, woutbf, bout, out, nullptr, 8192, 1024, 1024);
}

// Round 5
// 329.643 us; speedup vs baseline: 1.5112x; 1.2514x over previous
//
#include <hip/hip_runtime.h>
#include <stdint.h>

#define DEV __device__ __forceinline__

typedef unsigned short u16;
typedef __bf16 bf16x8 __attribute__((ext_vector_type(8)));
typedef float f32x4 __attribute__((ext_vector_type(4)));
typedef u16 u16x8 __attribute__((ext_vector_type(8)));

#define MFMA_BF16(A, B, C) __builtin_amdgcn_mfma_f32_16x16x32_bf16(A, B, C, 0, 0, 0)
#define EXP2(x) __builtin_amdgcn_exp2f(x)

DEV u16 f2bf(float f) {
    unsigned x;
    __builtin_memcpy(&x, &f, 4);
    unsigned r = (x + 0x7fffu + ((x >> 16) & 1u)) >> 16;  // RNE
    return (u16)r;
}

DEV void storeC(u16* p, float v) { *p = f2bf(v); }
DEV void storeC(float* p, float v) { *p = v; }

// async global->LDS, 16B per lane. LDS dest must be wave-uniform base + lane*16.
DEV void async_copy16(const u16* g, u16* l) {
    __builtin_amdgcn_global_load_lds(
        (__attribute__((address_space(1))) unsigned int*)g,
        (__attribute__((address_space(3))) unsigned int*)l, 16, 0, 0);
}

// ---------------------------------------------------------------------------
// fp32 -> bf16 conversion, 4 elems/thread.
// ---------------------------------------------------------------------------
__global__ __launch_bounds__(256)
void cvt_f32_bf16(const float* __restrict__ in, u16* __restrict__ out, int n) {
    const int i = (blockIdx.x * 256 + threadIdx.x) * 4;
    if (i < n) {
        const float4 v = *(const float4*)(in + i);
        ushort4 o;
        o.x = f2bf(v.x);
        o.y = f2bf(v.y);
        o.z = f2bf(v.z);
        o.w = f2bf(v.w);
        *(ushort4*)(out + i) = o;
    }
}

// ---------------------------------------------------------------------------
// C[M,N] = A[M,K] * Bw[N,K]^T + bias[N]; A,Bw bf16, bias fp32, fp32 accum.
// 128x128 tile, BK=32, 4 waves 2x2, each wave 64x64 via 4x4 MFMA 16x16x32.
// VSPLIT: cols >= 2048 (the V third of QKV) are stored TRANSPOSED into
// vT[col-2048][M] as packed ushort4 (4 consecutive tokens), not into C.
// ---------------------------------------------------------------------------
template <typename OT, bool VSPLIT>
__global__ __launch_bounds__(256, 2)
void gemm_bt_bias(const u16* __restrict__ A, const u16* __restrict__ Bw,
                  const float* __restrict__ bias, OT* __restrict__ C,
                  u16* __restrict__ vT, int M, int N, int K) {
    __shared__ __attribute__((aligned(16))) u16 sA[128 * 32];
    __shared__ __attribute__((aligned(16))) u16 sB[128 * 32];

    const int tid  = threadIdx.x;
    const int lane = tid & 63;
    const int wave = tid >> 6;
    const int m0 = blockIdx.y * 128;
    const int n0 = blockIdx.x * 128;
    const int wm = (wave & 1) * 64;
    const int wn = (wave >> 1) * 64;
    const int fr = lane & 15;
    const int q4 = lane >> 4;

    const int r0 = tid >> 2;
    const int c0 = (tid & 3) * 8;
    const u16* gA0 = A + (size_t)(m0 + r0) * K + c0;
    const u16* gA1 = A + (size_t)(m0 + 64 + r0) * K + c0;
    const u16* gB0 = Bw + (size_t)(n0 + r0) * K + c0;
    const u16* gB1 = Bw + (size_t)(n0 + 64 + r0) * K + c0;
    u16* lA0 = &sA[tid * 8];
    u16* lA1 = &sA[2048 + tid * 8];
    u16* lB0 = &sB[tid * 8];
    u16* lB1 = &sB[2048 + tid * 8];

    f32x4 acc[4][4];
#pragma unroll
    for (int i = 0; i < 4; i++)
#pragma unroll
        for (int j = 0; j < 4; j++) acc[i][j] = (f32x4){0.f, 0.f, 0.f, 0.f};

    for (int k0 = 0; k0 < K; k0 += 32) {
        async_copy16(gA0 + k0, lA0);
        async_copy16(gA1 + k0, lA1);
        async_copy16(gB0 + k0, lB0);
        async_copy16(gB1 + k0, lB1);
        __syncthreads();

        bf16x8 af[4], bfr[4];
#pragma unroll
        for (int i = 0; i < 4; i++)
            af[i] = *(const bf16x8*)&sA[(wm + i * 16 + fr) * 32 + q4 * 8];
#pragma unroll
        for (int j = 0; j < 4; j++)
            bfr[j] = *(const bf16x8*)&sB[(wn + j * 16 + fr) * 32 + q4 * 8];
#pragma unroll
        for (int i = 0; i < 4; i++)
#pragma unroll
            for (int j = 0; j < 4; j++)
                acc[i][j] = MFMA_BF16(af[i], bfr[j], acc[i][j]);
        __syncthreads();
    }

    // epilogue: C/D layout col=lane&15, row=quad*4+reg  [verified m89/m91]
#pragma unroll
    for (int j = 0; j < 4; j++) {
        const int col = n0 + wn + j * 16 + fr;
        const float bv = bias[col];
        if (VSPLIT && col >= 2048) {  // wave-uniform: col/16 uniform across fr
#pragma unroll
            for (int i = 0; i < 4; i++) {
                const int row = m0 + wm + i * 16 + q4 * 4;
                ushort4 o;
                o.x = f2bf(acc[i][j][0] + bv);
                o.y = f2bf(acc[i][j][1] + bv);
                o.z = f2bf(acc[i][j][2] + bv);
                o.w = f2bf(acc[i][j][3] + bv);
                *(ushort4*)&vT[(size_t)(col - 2048) * 8192 + row] = o;
            }
        } else {
#pragma unroll
            for (int i = 0; i < 4; i++) {
                const int row = m0 + wm + i * 16 + q4 * 4;
#pragma unroll
                for (int r = 0; r < 4; r++)
                    storeC(&C[(size_t)(row + r) * N + col], acc[i][j][r] + bv);
            }
        }
    }
}

// ---------------------------------------------------------------------------
// Flash attention, causal, S^T/O^T formulation.
//   S^T = K Q^T  (A-frag = K rows from sK, B-frag = Q register frag)
//     -> C-layout: row = key (q4*4+r), col = q (fr). Row-softmax over keys is
//        15 in-register fmax + 2 shfls; m/l/alpha are per-lane scalars.
//   P stored as sP[q][key]: packed ushort4 per t (reg dim r = contiguous keys).
//   O^T = V^T P^T (A-frag = sVT rows, B-frag = sP rows)
//     -> C-layout row = d, col = q (fr); alpha rescale = scalar mul.
// Staging is register-pipelined: next K/V tile preloaded right after barrier.
// ---------------------------------------------------------------------------
constexpr int Lc = 2048, Dc = 1024;

__global__ __launch_bounds__(256, 4)
void attn_fa(const u16* __restrict__ qkv, const u16* __restrict__ vT,
             u16* __restrict__ outb) {
    __shared__ __attribute__((aligned(16))) u16 sK[64 * 72];     // [key][d] pad 72
    __shared__ __attribute__((aligned(16))) u16 sVT[64 * 72];    // [d][key] pad 72
    __shared__ __attribute__((aligned(16))) u16 sP[4][16 * 72];  // per-wave [q][key]

    const int tid  = threadIdx.x;
    const int lane = tid & 63;
    const int wave = tid >> 6;
    const int fr = lane & 15;
    const int q4 = lane >> 4;
    const int qblk = 31 - blockIdx.x;  // longest blocks first
    const int h = blockIdx.y;
    const int b = blockIdx.z;

    constexpr float CEXP = 0.18033688011112042f;  // 0.125 * log2(e)

    // Q fragment (B-operand: n=lane&15 -> q row, k=q4*8+j -> d)
    const int qrow = qblk * 64 + wave * 16 + fr;
    const u16* qptr = qkv + ((size_t)(b * Lc + qrow) * 3) * Dc + h * 64;
    bf16x8 qf[2];
    qf[0] = *(const bf16x8*)(qptr + q4 * 8);
    qf[1] = *(const bf16x8*)(qptr + 32 + q4 * 8);

    f32x4 o_acc[4];
#pragma unroll
    for (int t = 0; t < 4; t++) o_acc[t] = (f32x4){0.f, 0.f, 0.f, 0.f};
    float m_i = -3.4e38f, l_i = 0.f;

    const int q_local = wave * 16 + fr;

    // staging: rr = row within half-tile, oo = 16B chunk
    const int rr = tid >> 3;
    const int oo = tid & 7;
    const u16* kg = qkv + ((size_t)(b * Lc) * 3 + 1) * Dc + h * 64 + oo * 8;  // + tok*3072
    const u16* vg = vT + (size_t)(h * 64) * 8192 + b * Lc + oo * 8;           // + d*8192 + key

    u16x8 kr[2], vr[2];
#pragma unroll
    for (int c = 0; c < 2; ++c) {
        kr[c] = *(const u16x8*)(kg + (size_t)(c * 32 + rr) * 3072);
        vr[c] = *(const u16x8*)(vg + (size_t)(c * 32 + rr) * 8192);
    }

    for (int jb = 0; jb <= qblk; ++jb) {
        __syncthreads();  // previous iteration's LDS reads complete
#pragma unroll
        for (int c = 0; c < 2; ++c) {
            *(u16x8*)&sK[(c * 32 + rr) * 72 + oo * 8] = kr[c];
            *(u16x8*)&sVT[(c * 32 + rr) * 72 + oo * 8] = vr[c];
        }
        __syncthreads();
        if (jb < qblk) {  // preload next tile; latency overlaps compute below
#pragma unroll
            for (int c = 0; c < 2; ++c) {
                kr[c] = *(const u16x8*)(kg + (size_t)((jb + 1) * 64 + c * 32 + rr) * 3072);
                vr[c] = *(const u16x8*)(vg + (size_t)(c * 32 + rr) * 8192 + (jb + 1) * 64);
            }
        }

        // S^T = K Q^T : row = key(local) = t*16 + q4*4 + r, col = q = fr
        f32x4 s[4];
#pragma unroll
        for (int t = 0; t < 4; t++) {
            s[t] = (f32x4){0.f, 0.f, 0.f, 0.f};
            s[t] = MFMA_BF16(*(const bf16x8*)&sK[(t * 16 + fr) * 72 + q4 * 8], qf[0], s[t]);
            s[t] = MFMA_BF16(*(const bf16x8*)&sK[(t * 16 + fr) * 72 + 32 + q4 * 8], qf[1], s[t]);
        }

        // causal mask only on the diagonal tile (raw scores; scale folded in exp)
        if (jb == qblk) {
#pragma unroll
            for (int t = 0; t < 4; t++)
#pragma unroll
                for (int r = 0; r < 4; r++)
                    if (t * 16 + q4 * 4 + r > q_local) s[t][r] = -1e30f;
        }

        // row max over keys: 15 in-register fmax + 2 shfls across q4 groups
        float mx = s[0][0];
#pragma unroll
        for (int t = 0; t < 4; t++)
#pragma unroll
            for (int r = 0; r < 4; r++) mx = fmaxf(mx, s[t][r]);
        mx = fmaxf(mx, __shfl_xor(mx, 16));
        mx = fmaxf(mx, __shfl_xor(mx, 32));
        const float mnew = fmaxf(m_i, mx);
        const float alpha = EXP2((m_i - mnew) * CEXP);

        float sum = 0.f;
#pragma unroll
        for (int t = 0; t < 4; t++) {
#pragma unroll
            for (int r = 0; r < 4; r++) {
                const float p = EXP2((s[t][r] - mnew) * CEXP);
                s[t][r] = p;
                sum += p;
            }
            ushort4 o;
            o.x = f2bf(s[t][0]);
            o.y = f2bf(s[t][1]);
            o.z = f2bf(s[t][2]);
            o.w = f2bf(s[t][3]);
            *(ushort4*)&sP[wave][fr * 72 + t * 16 + q4 * 4] = o;
        }
        sum += __shfl_xor(sum, 16);
        sum += __shfl_xor(sum, 32);
        l_i = alpha * l_i + sum;
        m_i = mnew;
#pragma unroll
        for (int t = 0; t < 4; t++)
#pragma unroll
            for (int r = 0; r < 4; r++) o_acc[t][r] *= alpha;

        // O^T += V^T P^T (wave-local sP write->read; DS is in-order per wave)
#pragma unroll
        for (int ks = 0; ks < 2; ++ks) {
            const bf16x8 pf = *(const bf16x8*)&sP[wave][fr * 72 + ks * 32 + q4 * 8];
#pragma unroll
            for (int t = 0; t < 4; t++) {
                const bf16x8 vf = *(const bf16x8*)&sVT[(t * 16 + fr) * 72 + ks * 32 + q4 * 8];
                o_acc[t] = MFMA_BF16(vf, pf, o_acc[t]);
            }
        }
    }

    // epilogue: O^T row = d = t*16+q4*4+r, col = q = fr -> packed ushort4
    const float rl = 1.0f / l_i;
    u16* orow = outb + (size_t)(b * Lc + qblk * 64 + wave * 16 + fr) * Dc + h * 64;
#pragma unroll
    for (int t = 0; t < 4; t++) {
        ushort4 o;
        o.x = f2bf(o_acc[t][0] * rl);
        o.y = f2bf(o_acc[t][1] * rl);
        o.z = f2bf(o_acc[t][2] * rl);
        o.w = f2bf(o_acc[t][3] * rl);
        *(ushort4*)(orow + t * 16 + q4 * 4) = o;
    }
}

// ---------------------------------------------------------------------------
extern "C" void kernel_launch(void* const* d_in, const int* in_sizes, int n_in,
                              void* d_out, int out_size, void* d_ws, size_t ws_size,
                              hipStream_t stream) {
    const float* x    = (const float*)d_in[0];  // [4,2048,1024] fp32
    const float* wqkv = (const float*)d_in[1];  // [3072,1024]
    const float* bqkv = (const float*)d_in[2];  // [3072]
    const float* wout = (const float*)d_in[3];  // [1024,1024]
    const float* bout = (const float*)d_in[4];  // [1024]
    float* out = (float*)d_out;                 // [4,2048,1024] fp32

    u16* qkv    = (u16*)d_ws;                       // [8192,3072] bf16 (V third unused)
    u16* attn   = qkv + (size_t)8192 * 3072;        // [8192,1024] bf16
    u16* xbf    = attn + (size_t)8192 * 1024;       // [8192,1024] bf16
    u16* wqkvbf = xbf + (size_t)8192 * 1024;        // [3072,1024] bf16
    u16* woutbf = wqkvbf + (size_t)3072 * 1024;     // [1024,1024] bf16
    u16* vT     = woutbf + (size_t)1024 * 1024;     // [1024, 8192] bf16 (V transposed)

    dim3 blk(256);
    cvt_f32_bf16<<<8192 * 1024 / 1024, blk, 0, stream>>>(x, xbf, 8192 * 1024);
    cvt_f32_bf16<<<3072 * 1024 / 1024, blk, 0, stream>>>(wqkv, wqkvbf, 3072 * 1024);
    cvt_f32_bf16<<<1024 * 1024 / 1024, blk, 0, stream>>>(wout, woutbf, 1024 * 1024);

    gemm_bt_bias<u16, true><<<dim3(3072 / 128, 8192 / 128), blk, 0, stream>>>(
        xbf, wqkvbf, bqkv, qkv, vT, 8192, 3072, 1024);
    attn_fa<<<dim3(32, 16, 4), blk, 0, stream>>>(qkv, vT, attn);
    gemm_bt_bias<float, false><<<dim3(1024 / 128, 8192 / 128), blk, 0, stream>>>(
        attn, woutbf, bout, out, nullptr, 8192, 1024, 1024);
}

// Round 6
// 311.718 us; speedup vs baseline: 1.5981x; 1.0575x over previous
//
#include <hip/hip_runtime.h>
#include <stdint.h>

#define DEV __device__ __forceinline__

typedef unsigned short u16;
typedef __bf16 bf16x8 __attribute__((ext_vector_type(8)));
typedef float f32x4 __attribute__((ext_vector_type(4)));
typedef u16 u16x8 __attribute__((ext_vector_type(8)));

#define MFMA_BF16(A, B, C) __builtin_amdgcn_mfma_f32_16x16x32_bf16(A, B, C, 0, 0, 0)
#define EXP2(x) __builtin_amdgcn_exp2f(x)

DEV u16 f2bf(float f) {
    unsigned x;
    __builtin_memcpy(&x, &f, 4);
    unsigned r = (x + 0x7fffu + ((x >> 16) & 1u)) >> 16;  // RNE
    return (u16)r;
}

DEV u16 f2bf_fast(float f) {  // round-half-up; 2 VALU ops, used in attn hot loop
    unsigned x;
    __builtin_memcpy(&x, &f, 4);
    return (u16)((x + 0x8000u) >> 16);
}

DEV void storeC(u16* p, float v) { *p = f2bf(v); }
DEV void storeC(float* p, float v) { *p = v; }

// async global->LDS, 16B per lane. LDS dest must be wave-uniform base + lane*16.
DEV void async_copy16(const u16* g, u16* l) {
    __builtin_amdgcn_global_load_lds(
        (__attribute__((address_space(1))) unsigned int*)g,
        (__attribute__((address_space(3))) unsigned int*)l, 16, 0, 0);
}

// ---------------------------------------------------------------------------
// fp32 -> bf16 conversion, 4 elems/thread.
// ---------------------------------------------------------------------------
__global__ __launch_bounds__(256)
void cvt_f32_bf16(const float* __restrict__ in, u16* __restrict__ out, int n) {
    const int i = (blockIdx.x * 256 + threadIdx.x) * 4;
    if (i < n) {
        const float4 v = *(const float4*)(in + i);
        ushort4 o;
        o.x = f2bf(v.x);
        o.y = f2bf(v.y);
        o.z = f2bf(v.z);
        o.w = f2bf(v.w);
        *(ushort4*)(out + i) = o;
    }
}

// ---------------------------------------------------------------------------
// C[M,N] = A[M,K] * Bw[N,K]^T + bias[N]; A,Bw bf16, bias fp32, fp32 accum.
// 128x128 tile, BK=32, 4 waves 2x2, each wave 64x64 via 4x4 MFMA 16x16x32.
// VSPLIT: cols >= 2048 (the V third of QKV) are stored TRANSPOSED into
// vT[col-2048][M] as packed ushort4 (4 consecutive tokens), not into C.
// ---------------------------------------------------------------------------
template <typename OT, bool VSPLIT>
__global__ __launch_bounds__(256, 2)
void gemm_bt_bias(const u16* __restrict__ A, const u16* __restrict__ Bw,
                  const float* __restrict__ bias, OT* __restrict__ C,
                  u16* __restrict__ vT, int M, int N, int K) {
    __shared__ __attribute__((aligned(16))) u16 sA[128 * 32];
    __shared__ __attribute__((aligned(16))) u16 sB[128 * 32];

    const int tid  = threadIdx.x;
    const int lane = tid & 63;
    const int wave = tid >> 6;
    const int m0 = blockIdx.y * 128;
    const int n0 = blockIdx.x * 128;
    const int wm = (wave & 1) * 64;
    const int wn = (wave >> 1) * 64;
    const int fr = lane & 15;
    const int q4 = lane >> 4;

    const int r0 = tid >> 2;
    const int c0 = (tid & 3) * 8;
    const u16* gA0 = A + (size_t)(m0 + r0) * K + c0;
    const u16* gA1 = A + (size_t)(m0 + 64 + r0) * K + c0;
    const u16* gB0 = Bw + (size_t)(n0 + r0) * K + c0;
    const u16* gB1 = Bw + (size_t)(n0 + 64 + r0) * K + c0;
    u16* lA0 = &sA[tid * 8];
    u16* lA1 = &sA[2048 + tid * 8];
    u16* lB0 = &sB[tid * 8];
    u16* lB1 = &sB[2048 + tid * 8];

    f32x4 acc[4][4];
#pragma unroll
    for (int i = 0; i < 4; i++)
#pragma unroll
        for (int j = 0; j < 4; j++) acc[i][j] = (f32x4){0.f, 0.f, 0.f, 0.f};

    for (int k0 = 0; k0 < K; k0 += 32) {
        async_copy16(gA0 + k0, lA0);
        async_copy16(gA1 + k0, lA1);
        async_copy16(gB0 + k0, lB0);
        async_copy16(gB1 + k0, lB1);
        __syncthreads();

        bf16x8 af[4], bfr[4];
#pragma unroll
        for (int i = 0; i < 4; i++)
            af[i] = *(const bf16x8*)&sA[(wm + i * 16 + fr) * 32 + q4 * 8];
#pragma unroll
        for (int j = 0; j < 4; j++)
            bfr[j] = *(const bf16x8*)&sB[(wn + j * 16 + fr) * 32 + q4 * 8];
#pragma unroll
        for (int i = 0; i < 4; i++)
#pragma unroll
            for (int j = 0; j < 4; j++)
                acc[i][j] = MFMA_BF16(af[i], bfr[j], acc[i][j]);
        __syncthreads();
    }

    // epilogue: C/D layout col=lane&15, row=quad*4+reg  [verified m89/m91]
#pragma unroll
    for (int j = 0; j < 4; j++) {
        const int col = n0 + wn + j * 16 + fr;
        const float bv = bias[col];
        if (VSPLIT && col >= 2048) {  // wave-uniform: col/16 uniform across fr
#pragma unroll
            for (int i = 0; i < 4; i++) {
                const int row = m0 + wm + i * 16 + q4 * 4;
                ushort4 o;
                o.x = f2bf(acc[i][j][0] + bv);
                o.y = f2bf(acc[i][j][1] + bv);
                o.z = f2bf(acc[i][j][2] + bv);
                o.w = f2bf(acc[i][j][3] + bv);
                *(ushort4*)&vT[(size_t)(col - 2048) * 8192 + row] = o;
            }
        } else {
#pragma unroll
            for (int i = 0; i < 4; i++) {
                const int row = m0 + wm + i * 16 + q4 * 4;
#pragma unroll
                for (int r = 0; r < 4; r++)
                    storeC(&C[(size_t)(row + r) * N + col], acc[i][j][r] + bv);
            }
        }
    }
}

// ---------------------------------------------------------------------------
// Flash attention, causal, S^T/O^T formulation, PAIRED Q-TILES.
// Block (bx, h, b) owns q-tiles qA = bx and qB = 31-bx (64 rows each) of one
// (b,h): the K/V tile staged per jb serves 128 q rows, halving staging,
// barriers, and sK/sVT fragment reads per unit work; per-block work is
// uniform (33 tile-softmax units), killing the dispatch tail.
//   S^T = K Q^T : C-layout row = key (q4*4+r), col = q (fr); softmax state is
//   per-lane scalar; P packed ushort4; O^T = V^T P^T.
// ---------------------------------------------------------------------------
constexpr int Lc = 2048, Dc = 1024;

__global__ __launch_bounds__(256, 4)
void attn_fa(const u16* __restrict__ qkv, const u16* __restrict__ vT,
             u16* __restrict__ outb) {
    __shared__ __attribute__((aligned(16))) u16 sK[64 * 72];        // [key][d]
    __shared__ __attribute__((aligned(16))) u16 sVT[64 * 72];       // [d][key]
    __shared__ __attribute__((aligned(16))) u16 sP[4][2][16 * 72];  // [wave][tile][q][key]

    const int tid  = threadIdx.x;
    const int lane = tid & 63;
    const int wave = tid >> 6;
    const int fr = lane & 15;
    const int q4 = lane >> 4;
    const int bx = blockIdx.x;         // 0..15
    const int qblkA = bx;              // short tile
    const int qblkB = 31 - bx;        // long tile
    const int h = blockIdx.y;
    const int b = blockIdx.z;

    constexpr float CEXP = 0.18033688011112042f;  // 0.125 * log2(e)

    // Q fragments (B-operand: n=fr -> q row, k=q4*8+j -> d)
    const int qrowA = qblkA * 64 + wave * 16 + fr;
    const int qrowB = qblkB * 64 + wave * 16 + fr;
    const u16* qptrA = qkv + ((size_t)(b * Lc + qrowA) * 3) * Dc + h * 64;
    const u16* qptrB = qkv + ((size_t)(b * Lc + qrowB) * 3) * Dc + h * 64;
    bf16x8 qfA[2], qfB[2];
    qfA[0] = *(const bf16x8*)(qptrA + q4 * 8);
    qfA[1] = *(const bf16x8*)(qptrA + 32 + q4 * 8);
    qfB[0] = *(const bf16x8*)(qptrB + q4 * 8);
    qfB[1] = *(const bf16x8*)(qptrB + 32 + q4 * 8);

    f32x4 oA[4], oB[4];
#pragma unroll
    for (int t = 0; t < 4; t++) {
        oA[t] = (f32x4){0.f, 0.f, 0.f, 0.f};
        oB[t] = (f32x4){0.f, 0.f, 0.f, 0.f};
    }
    float mA = -3.4e38f, lA = 0.f, mB = -3.4e38f, lB = 0.f;

    const int q_local = wave * 16 + fr;

    // staging: rr = row within half-tile, oo = 16B chunk
    const int rr = tid >> 3;
    const int oo = tid & 7;
    const u16* kg = qkv + ((size_t)(b * Lc) * 3 + 1) * Dc + h * 64 + oo * 8;  // + tok*3072
    const u16* vg = vT + (size_t)(h * 64) * 8192 + b * Lc + oo * 8;           // + d*8192 + key

    u16x8 kr[2], vr[2];
#pragma unroll
    for (int c = 0; c < 2; ++c) {
        kr[c] = *(const u16x8*)(kg + (size_t)(c * 32 + rr) * 3072);
        vr[c] = *(const u16x8*)(vg + (size_t)(c * 32 + rr) * 8192);
    }

    u16* sPA = &sP[wave][0][0];
    u16* sPB = &sP[wave][1][0];

    for (int jb = 0; jb <= qblkB; ++jb) {
        __syncthreads();  // previous iteration's LDS reads complete
#pragma unroll
        for (int c = 0; c < 2; ++c) {
            *(u16x8*)&sK[(c * 32 + rr) * 72 + oo * 8] = kr[c];
            *(u16x8*)&sVT[(c * 32 + rr) * 72 + oo * 8] = vr[c];
        }
        __syncthreads();
        if (jb < qblkB) {  // preload next tile; latency overlaps compute below
#pragma unroll
            for (int c = 0; c < 2; ++c) {
                kr[c] = *(const u16x8*)(kg + (size_t)((jb + 1) * 64 + c * 32 + rr) * 3072);
                vr[c] = *(const u16x8*)(vg + (size_t)(c * 32 + rr) * 8192 + (jb + 1) * 64);
            }
        }

        const bool doA = (jb <= qblkA);  // wave-uniform

        // S^T = K Q^T for both tiles, sharing the K-fragment reads
        f32x4 sA_[4], sB_[4];
#pragma unroll
        for (int t = 0; t < 4; t++) {
            const bf16x8 kf0 = *(const bf16x8*)&sK[(t * 16 + fr) * 72 + q4 * 8];
            const bf16x8 kf1 = *(const bf16x8*)&sK[(t * 16 + fr) * 72 + 32 + q4 * 8];
            sB_[t] = (f32x4){0.f, 0.f, 0.f, 0.f};
            sB_[t] = MFMA_BF16(kf0, qfB[0], sB_[t]);
            sB_[t] = MFMA_BF16(kf1, qfB[1], sB_[t]);
            if (doA) {
                sA_[t] = (f32x4){0.f, 0.f, 0.f, 0.f};
                sA_[t] = MFMA_BF16(kf0, qfA[0], sA_[t]);
                sA_[t] = MFMA_BF16(kf1, qfA[1], sA_[t]);
            }
        }

        // ---- tile B softmax ----
        {
            if (jb == qblkB) {
#pragma unroll
                for (int t = 0; t < 4; t++)
#pragma unroll
                    for (int r = 0; r < 4; r++)
                        if (t * 16 + q4 * 4 + r > q_local) sB_[t][r] = -1e30f;
            }
            float mx = sB_[0][0];
#pragma unroll
            for (int t = 0; t < 4; t++)
#pragma unroll
                for (int r = 0; r < 4; r++) mx = fmaxf(mx, sB_[t][r]);
            mx = fmaxf(mx, __shfl_xor(mx, 16));
            mx = fmaxf(mx, __shfl_xor(mx, 32));
            const float mnew = fmaxf(mB, mx);
            const float alpha = EXP2((mB - mnew) * CEXP);
            float sum = 0.f;
#pragma unroll
            for (int t = 0; t < 4; t++) {
#pragma unroll
                for (int r = 0; r < 4; r++) {
                    const float p = EXP2((sB_[t][r] - mnew) * CEXP);
                    sB_[t][r] = p;
                    sum += p;
                }
                ushort4 o;
                o.x = f2bf_fast(sB_[t][0]);
                o.y = f2bf_fast(sB_[t][1]);
                o.z = f2bf_fast(sB_[t][2]);
                o.w = f2bf_fast(sB_[t][3]);
                *(ushort4*)&sPB[fr * 72 + t * 16 + q4 * 4] = o;
            }
            sum += __shfl_xor(sum, 16);
            sum += __shfl_xor(sum, 32);
            lB = alpha * lB + sum;
            mB = mnew;
#pragma unroll
            for (int t = 0; t < 4; t++)
#pragma unroll
                for (int r = 0; r < 4; r++) oB[t][r] *= alpha;
        }

        // ---- tile A softmax ----
        if (doA) {
            if (jb == qblkA) {
#pragma unroll
                for (int t = 0; t < 4; t++)
#pragma unroll
                    for (int r = 0; r < 4; r++)
                        if (t * 16 + q4 * 4 + r > q_local) sA_[t][r] = -1e30f;
            }
            float mx = sA_[0][0];
#pragma unroll
            for (int t = 0; t < 4; t++)
#pragma unroll
                for (int r = 0; r < 4; r++) mx = fmaxf(mx, sA_[t][r]);
            mx = fmaxf(mx, __shfl_xor(mx, 16));
            mx = fmaxf(mx, __shfl_xor(mx, 32));
            const float mnew = fmaxf(mA, mx);
            const float alpha = EXP2((mA - mnew) * CEXP);
            float sum = 0.f;
#pragma unroll
            for (int t = 0; t < 4; t++) {
#pragma unroll
                for (int r = 0; r < 4; r++) {
                    const float p = EXP2((sA_[t][r] - mnew) * CEXP);
                    sA_[t][r] = p;
                    sum += p;
                }
                ushort4 o;
                o.x = f2bf_fast(sA_[t][0]);
                o.y = f2bf_fast(sA_[t][1]);
                o.z = f2bf_fast(sA_[t][2]);
                o.w = f2bf_fast(sA_[t][3]);
                *(ushort4*)&sPA[fr * 72 + t * 16 + q4 * 4] = o;
            }
            sum += __shfl_xor(sum, 16);
            sum += __shfl_xor(sum, 32);
            lA = alpha * lA + sum;
            mA = mnew;
#pragma unroll
            for (int t = 0; t < 4; t++)
#pragma unroll
                for (int r = 0; r < 4; r++) oA[t][r] *= alpha;
        }

        // O^T += V^T P^T, sharing the V-fragment reads (wave-local sP; DS in-order)
#pragma unroll
        for (int ks = 0; ks < 2; ++ks) {
            const bf16x8 pfB = *(const bf16x8*)&sPB[fr * 72 + ks * 32 + q4 * 8];
            bf16x8 pfA;
            if (doA) pfA = *(const bf16x8*)&sPA[fr * 72 + ks * 32 + q4 * 8];
#pragma unroll
            for (int t = 0; t < 4; t++) {
                const bf16x8 vf = *(const bf16x8*)&sVT[(t * 16 + fr) * 72 + ks * 32 + q4 * 8];
                oB[t] = MFMA_BF16(vf, pfB, oB[t]);
                if (doA) oA[t] = MFMA_BF16(vf, pfA, oA[t]);
            }
        }
    }

    // epilogue: O^T row = d = t*16+q4*4+r, col = q = fr -> packed ushort4
    const float rlA = 1.0f / lA;
    const float rlB = 1.0f / lB;
    u16* orowA = outb + (size_t)(b * Lc + qblkA * 64 + wave * 16 + fr) * Dc + h * 64;
    u16* orowB = outb + (size_t)(b * Lc + qblkB * 64 + wave * 16 + fr) * Dc + h * 64;
#pragma unroll
    for (int t = 0; t < 4; t++) {
        ushort4 a, o;
        a.x = f2bf(oA[t][0] * rlA);
        a.y = f2bf(oA[t][1] * rlA);
        a.z = f2bf(oA[t][2] * rlA);
        a.w = f2bf(oA[t][3] * rlA);
        *(ushort4*)(orowA + t * 16 + q4 * 4) = a;
        o.x = f2bf(oB[t][0] * rlB);
        o.y = f2bf(oB[t][1] * rlB);
        o.z = f2bf(oB[t][2] * rlB);
        o.w = f2bf(oB[t][3] * rlB);
        *(ushort4*)(orowB + t * 16 + q4 * 4) = o;
    }
}

// ---------------------------------------------------------------------------
extern "C" void kernel_launch(void* const* d_in, const int* in_sizes, int n_in,
                              void* d_out, int out_size, void* d_ws, size_t ws_size,
                              hipStream_t stream) {
    const float* x    = (const float*)d_in[0];  // [4,2048,1024] fp32
    const float* wqkv = (const float*)d_in[1];  // [3072,1024]
    const float* bqkv = (const float*)d_in[2];  // [3072]
    const float* wout = (const float*)d_in[3];  // [1024,1024]
    const float* bout = (const float*)d_in[4];  // [1024]
    float* out = (float*)d_out;                 // [4,2048,1024] fp32

    u16* qkv    = (u16*)d_ws;                       // [8192,3072] bf16 (V third unused)
    u16* attn   = qkv + (size_t)8192 * 3072;        // [8192,1024] bf16
    u16* xbf    = attn + (size_t)8192 * 1024;       // [8192,1024] bf16
    u16* wqkvbf = xbf + (size_t)8192 * 1024;        // [3072,1024] bf16
    u16* woutbf = wqkvbf + (size_t)3072 * 1024;     // [1024,1024] bf16
    u16* vT     = woutbf + (size_t)1024 * 1024;     // [1024, 8192] bf16 (V transposed)

    dim3 blk(256);
    cvt_f32_bf16<<<8192 * 1024 / 1024, blk, 0, stream>>>(x, xbf, 8192 * 1024);
    cvt_f32_bf16<<<3072 * 1024 / 1024, blk, 0, stream>>>(wqkv, wqkvbf, 3072 * 1024);
    cvt_f32_bf16<<<1024 * 1024 / 1024, blk, 0, stream>>>(wout, woutbf, 1024 * 1024);

    gemm_bt_bias<u16, true><<<dim3(3072 / 128, 8192 / 128), blk, 0, stream>>>(
        xbf, wqkvbf, bqkv, qkv, vT, 8192, 3072, 1024);
    attn_fa<<<dim3(16, 16, 4), blk, 0, stream>>>(qkv, vT, attn);
    gemm_bt_bias<float, false><<<dim3(1024 / 128, 8192 / 128), blk, 0, stream>>>(
        attn, woutbf, bout, out, nullptr, 8192, 1024, 1024);
}

// Round 7
// 293.584 us; speedup vs baseline: 1.6968x; 1.0618x over previous
//
#include <hip/hip_runtime.h>
#include <stdint.h>

#define DEV __device__ __forceinline__

typedef unsigned short u16;
typedef __bf16 bf16x8 __attribute__((ext_vector_type(8)));
typedef float f32x4 __attribute__((ext_vector_type(4)));
typedef u16 u16x8 __attribute__((ext_vector_type(8)));

#define MFMA_BF16(A, B, C) __builtin_amdgcn_mfma_f32_16x16x32_bf16(A, B, C, 0, 0, 0)
#define EXP2(x) __builtin_amdgcn_exp2f(x)

DEV u16 f2bf(float f) {
    unsigned x;
    __builtin_memcpy(&x, &f, 4);
    unsigned r = (x + 0x7fffu + ((x >> 16) & 1u)) >> 16;  // RNE
    return (u16)r;
}

DEV u16 f2bf_fast(float f) {  // round-half-up; 2 VALU ops, used in attn hot loop
    unsigned x;
    __builtin_memcpy(&x, &f, 4);
    return (u16)((x + 0x8000u) >> 16);
}

DEV void storeC(u16* p, float v) { *p = f2bf(v); }
DEV void storeC(float* p, float v) { *p = v; }

// async global->LDS, 16B per lane. LDS dest must be wave-uniform base + lane*16.
DEV void async_copy16(const u16* g, u16* l) {
    __builtin_amdgcn_global_load_lds(
        (__attribute__((address_space(1))) unsigned int*)g,
        (__attribute__((address_space(3))) unsigned int*)l, 16, 0, 0);
}

// ---------------------------------------------------------------------------
// fused fp32 -> bf16 conversion of x | wqkv | wout into one contiguous dest.
// ---------------------------------------------------------------------------
constexpr int N_X = 8192 * 1024, N_WQ = 3072 * 1024, N_WO = 1024 * 1024;

__global__ __launch_bounds__(256)
void cvt_all(const float* __restrict__ x, const float* __restrict__ wq,
             const float* __restrict__ wo, u16* __restrict__ out) {
    const int i = (blockIdx.x * 256 + threadIdx.x) * 4;
    const float* src;
    if (i < N_X) src = x + i;
    else if (i < N_X + N_WQ) src = wq + (i - N_X);
    else src = wo + (i - N_X - N_WQ);
    const float4 v = *(const float4*)src;
    ushort4 o;
    o.x = f2bf(v.x);
    o.y = f2bf(v.y);
    o.z = f2bf(v.z);
    o.w = f2bf(v.w);
    *(ushort4*)(out + i) = o;
}

// ---------------------------------------------------------------------------
// C[M,N] = A[M,K] * Bw[N,K]^T + bias[N]; A,Bw bf16, bias fp32, fp32 accum.
// 128x128 tile, BK=64 as two 32-wide panels (separate LDS buffers keep the
// conflict-free stride-32 layout AND the global_load_lds contiguity rule).
// Barrier pairs per K-loop: K/64 (half of BK=32).
// VSPLIT: cols >= 2048 (the V third of QKV) are stored TRANSPOSED into
// vT[col-2048][M] as packed ushort4, not into C.
// ---------------------------------------------------------------------------
template <typename OT, bool VSPLIT>
__global__ __launch_bounds__(256, 2)
void gemm_bt_bias(const u16* __restrict__ A, const u16* __restrict__ Bw,
                  const float* __restrict__ bias, OT* __restrict__ C,
                  u16* __restrict__ vT, int M, int N, int K) {
    __shared__ __attribute__((aligned(16))) u16 sA[2][128 * 32];
    __shared__ __attribute__((aligned(16))) u16 sB[2][128 * 32];

    const int tid  = threadIdx.x;
    const int lane = tid & 63;
    const int wave = tid >> 6;
    const int m0 = blockIdx.y * 128;
    const int n0 = blockIdx.x * 128;
    const int wm = (wave & 1) * 64;
    const int wn = (wave >> 1) * 64;
    const int fr = lane & 15;
    const int q4 = lane >> 4;

    const int r0 = tid >> 2;
    const int c0 = (tid & 3) * 8;
    const u16* gA0 = A + (size_t)(m0 + r0) * K + c0;
    const u16* gA1 = A + (size_t)(m0 + 64 + r0) * K + c0;
    const u16* gB0 = Bw + (size_t)(n0 + r0) * K + c0;
    const u16* gB1 = Bw + (size_t)(n0 + 64 + r0) * K + c0;

    f32x4 acc[4][4];
#pragma unroll
    for (int i = 0; i < 4; i++)
#pragma unroll
        for (int j = 0; j < 4; j++) acc[i][j] = (f32x4){0.f, 0.f, 0.f, 0.f};

    for (int k0 = 0; k0 < K; k0 += 64) {
#pragma unroll
        for (int p = 0; p < 2; ++p) {  // two 32-wide K panels
            async_copy16(gA0 + k0 + p * 32, &sA[p][tid * 8]);
            async_copy16(gA1 + k0 + p * 32, &sA[p][2048 + tid * 8]);
            async_copy16(gB0 + k0 + p * 32, &sB[p][tid * 8]);
            async_copy16(gB1 + k0 + p * 32, &sB[p][2048 + tid * 8]);
        }
        __syncthreads();

#pragma unroll
        for (int p = 0; p < 2; ++p) {
            bf16x8 af[4], bfr[4];
#pragma unroll
            for (int i = 0; i < 4; i++)
                af[i] = *(const bf16x8*)&sA[p][(wm + i * 16 + fr) * 32 + q4 * 8];
#pragma unroll
            for (int j = 0; j < 4; j++)
                bfr[j] = *(const bf16x8*)&sB[p][(wn + j * 16 + fr) * 32 + q4 * 8];
#pragma unroll
            for (int i = 0; i < 4; i++)
#pragma unroll
                for (int j = 0; j < 4; j++)
                    acc[i][j] = MFMA_BF16(af[i], bfr[j], acc[i][j]);
        }
        __syncthreads();
    }

    // epilogue: C/D layout col=lane&15, row=quad*4+reg  [verified m89/m91]
#pragma unroll
    for (int j = 0; j < 4; j++) {
        const int col = n0 + wn + j * 16 + fr;
        const float bv = bias[col];
        if (VSPLIT && col >= 2048) {  // wave-uniform: col/16 uniform across fr
#pragma unroll
            for (int i = 0; i < 4; i++) {
                const int row = m0 + wm + i * 16 + q4 * 4;
                ushort4 o;
                o.x = f2bf(acc[i][j][0] + bv);
                o.y = f2bf(acc[i][j][1] + bv);
                o.z = f2bf(acc[i][j][2] + bv);
                o.w = f2bf(acc[i][j][3] + bv);
                *(ushort4*)&vT[(size_t)(col - 2048) * 8192 + row] = o;
            }
        } else {
#pragma unroll
            for (int i = 0; i < 4; i++) {
                const int row = m0 + wm + i * 16 + q4 * 4;
#pragma unroll
                for (int r = 0; r < 4; r++)
                    storeC(&C[(size_t)(row + r) * N + col], acc[i][j][r] + bv);
            }
        }
    }
}

// ---------------------------------------------------------------------------
// Flash attention, causal, S^T/O^T formulation, PAIRED Q-TILES.
// Block (bx, h, b) owns q-tiles qA = bx and qB = 31-bx (64 rows each) of one
// (b,h): the K/V tile staged per jb serves 128 q rows.
//   S^T = K Q^T : C-layout row = key (q4*4+r), col = q (fr); softmax state is
//   per-lane scalar; P packed ushort4; O^T = V^T P^T.
// ---------------------------------------------------------------------------
constexpr int Lc = 2048, Dc = 1024;

__global__ __launch_bounds__(256, 4)
void attn_fa(const u16* __restrict__ qkv, const u16* __restrict__ vT,
             u16* __restrict__ outb) {
    __shared__ __attribute__((aligned(16))) u16 sK[64 * 72];        // [key][d]
    __shared__ __attribute__((aligned(16))) u16 sVT[64 * 72];       // [d][key]
    __shared__ __attribute__((aligned(16))) u16 sP[4][2][16 * 72];  // [wave][tile][q][key]

    const int tid  = threadIdx.x;
    const int lane = tid & 63;
    const int wave = tid >> 6;
    const int fr = lane & 15;
    const int q4 = lane >> 4;
    const int bx = blockIdx.x;         // 0..15
    const int qblkA = bx;              // short tile
    const int qblkB = 31 - bx;        // long tile
    const int h = blockIdx.y;
    const int b = blockIdx.z;

    constexpr float CEXP = 0.18033688011112042f;  // 0.125 * log2(e)

    // Q fragments (B-operand: n=fr -> q row, k=q4*8+j -> d)
    const int qrowA = qblkA * 64 + wave * 16 + fr;
    const int qrowB = qblkB * 64 + wave * 16 + fr;
    const u16* qptrA = qkv + ((size_t)(b * Lc + qrowA) * 3) * Dc + h * 64;
    const u16* qptrB = qkv + ((size_t)(b * Lc + qrowB) * 3) * Dc + h * 64;
    bf16x8 qfA[2], qfB[2];
    qfA[0] = *(const bf16x8*)(qptrA + q4 * 8);
    qfA[1] = *(const bf16x8*)(qptrA + 32 + q4 * 8);
    qfB[0] = *(const bf16x8*)(qptrB + q4 * 8);
    qfB[1] = *(const bf16x8*)(qptrB + 32 + q4 * 8);

    f32x4 oA[4], oB[4];
#pragma unroll
    for (int t = 0; t < 4; t++) {
        oA[t] = (f32x4){0.f, 0.f, 0.f, 0.f};
        oB[t] = (f32x4){0.f, 0.f, 0.f, 0.f};
    }
    float mA = -3.4e38f, lA = 0.f, mB = -3.4e38f, lB = 0.f;

    const int q_local = wave * 16 + fr;

    // staging: rr = row within half-tile, oo = 16B chunk
    const int rr = tid >> 3;
    const int oo = tid & 7;
    const u16* kg = qkv + ((size_t)(b * Lc) * 3 + 1) * Dc + h * 64 + oo * 8;  // + tok*3072
    const u16* vg = vT + (size_t)(h * 64) * 8192 + b * Lc + oo * 8;           // + d*8192 + key

    u16x8 kr[2], vr[2];
#pragma unroll
    for (int c = 0; c < 2; ++c) {
        kr[c] = *(const u16x8*)(kg + (size_t)(c * 32 + rr) * 3072);
        vr[c] = *(const u16x8*)(vg + (size_t)(c * 32 + rr) * 8192);
    }

    u16* sPA = &sP[wave][0][0];
    u16* sPB = &sP[wave][1][0];

    for (int jb = 0; jb <= qblkB; ++jb) {
        __syncthreads();  // previous iteration's LDS reads complete
#pragma unroll
        for (int c = 0; c < 2; ++c) {
            *(u16x8*)&sK[(c * 32 + rr) * 72 + oo * 8] = kr[c];
            *(u16x8*)&sVT[(c * 32 + rr) * 72 + oo * 8] = vr[c];
        }
        __syncthreads();
        if (jb < qblkB) {  // preload next tile; latency overlaps compute below
#pragma unroll
            for (int c = 0; c < 2; ++c) {
                kr[c] = *(const u16x8*)(kg + (size_t)((jb + 1) * 64 + c * 32 + rr) * 3072);
                vr[c] = *(const u16x8*)(vg + (size_t)(c * 32 + rr) * 8192 + (jb + 1) * 64);
            }
        }

        const bool doA = (jb <= qblkA);  // wave-uniform

        // S^T = K Q^T for both tiles, sharing the K-fragment reads
        f32x4 sA_[4], sB_[4];
#pragma unroll
        for (int t = 0; t < 4; t++) {
            const bf16x8 kf0 = *(const bf16x8*)&sK[(t * 16 + fr) * 72 + q4 * 8];
            const bf16x8 kf1 = *(const bf16x8*)&sK[(t * 16 + fr) * 72 + 32 + q4 * 8];
            sB_[t] = (f32x4){0.f, 0.f, 0.f, 0.f};
            sB_[t] = MFMA_BF16(kf0, qfB[0], sB_[t]);
            sB_[t] = MFMA_BF16(kf1, qfB[1], sB_[t]);
            if (doA) {
                sA_[t] = (f32x4){0.f, 0.f, 0.f, 0.f};
                sA_[t] = MFMA_BF16(kf0, qfA[0], sA_[t]);
                sA_[t] = MFMA_BF16(kf1, qfA[1], sA_[t]);
            }
        }

        // ---- tile B softmax ----
        {
            if (jb == qblkB) {
#pragma unroll
                for (int t = 0; t < 4; t++)
#pragma unroll
                    for (int r = 0; r < 4; r++)
                        if (t * 16 + q4 * 4 + r > q_local) sB_[t][r] = -1e30f;
            }
            float mx = sB_[0][0];
#pragma unroll
            for (int t = 0; t < 4; t++)
#pragma unroll
                for (int r = 0; r < 4; r++) mx = fmaxf(mx, sB_[t][r]);
            mx = fmaxf(mx, __shfl_xor(mx, 16));
            mx = fmaxf(mx, __shfl_xor(mx, 32));
            const float mnew = fmaxf(mB, mx);
            const float alpha = EXP2((mB - mnew) * CEXP);
            float sum = 0.f;
#pragma unroll
            for (int t = 0; t < 4; t++) {
#pragma unroll
                for (int r = 0; r < 4; r++) {
                    const float p = EXP2((sB_[t][r] - mnew) * CEXP);
                    sB_[t][r] = p;
                    sum += p;
                }
                ushort4 o;
                o.x = f2bf_fast(sB_[t][0]);
                o.y = f2bf_fast(sB_[t][1]);
                o.z = f2bf_fast(sB_[t][2]);
                o.w = f2bf_fast(sB_[t][3]);
                *(ushort4*)&sPB[fr * 72 + t * 16 + q4 * 4] = o;
            }
            sum += __shfl_xor(sum, 16);
            sum += __shfl_xor(sum, 32);
            lB = alpha * lB + sum;
            mB = mnew;
#pragma unroll
            for (int t = 0; t < 4; t++)
#pragma unroll
                for (int r = 0; r < 4; r++) oB[t][r] *= alpha;
        }

        // ---- tile A softmax ----
        if (doA) {
            if (jb == qblkA) {
#pragma unroll
                for (int t = 0; t < 4; t++)
#pragma unroll
                    for (int r = 0; r < 4; r++)
                        if (t * 16 + q4 * 4 + r > q_local) sA_[t][r] = -1e30f;
            }
            float mx = sA_[0][0];
#pragma unroll
            for (int t = 0; t < 4; t++)
#pragma unroll
                for (int r = 0; r < 4; r++) mx = fmaxf(mx, sA_[t][r]);
            mx = fmaxf(mx, __shfl_xor(mx, 16));
            mx = fmaxf(mx, __shfl_xor(mx, 32));
            const float mnew = fmaxf(mA, mx);
            const float alpha = EXP2((mA - mnew) * CEXP);
            float sum = 0.f;
#pragma unroll
            for (int t = 0; t < 4; t++) {
#pragma unroll
                for (int r = 0; r < 4; r++) {
                    const float p = EXP2((sA_[t][r] - mnew) * CEXP);
                    sA_[t][r] = p;
                    sum += p;
                }
                ushort4 o;
                o.x = f2bf_fast(sA_[t][0]);
                o.y = f2bf_fast(sA_[t][1]);
                o.z = f2bf_fast(sA_[t][2]);
                o.w = f2bf_fast(sA_[t][3]);
                *(ushort4*)&sPA[fr * 72 + t * 16 + q4 * 4] = o;
            }
            sum += __shfl_xor(sum, 16);
            sum += __shfl_xor(sum, 32);
            lA = alpha * lA + sum;
            mA = mnew;
#pragma unroll
            for (int t = 0; t < 4; t++)
#pragma unroll
                for (int r = 0; r < 4; r++) oA[t][r] *= alpha;
        }

        // O^T += V^T P^T, sharing the V-fragment reads (wave-local sP; DS in-order)
#pragma unroll
        for (int ks = 0; ks < 2; ++ks) {
            const bf16x8 pfB = *(const bf16x8*)&sPB[fr * 72 + ks * 32 + q4 * 8];
            bf16x8 pfA;
            if (doA) pfA = *(const bf16x8*)&sPA[fr * 72 + ks * 32 + q4 * 8];
#pragma unroll
            for (int t = 0; t < 4; t++) {
                const bf16x8 vf = *(const bf16x8*)&sVT[(t * 16 + fr) * 72 + ks * 32 + q4 * 8];
                oB[t] = MFMA_BF16(vf, pfB, oB[t]);
                if (doA) oA[t] = MFMA_BF16(vf, pfA, oA[t]);
            }
        }
    }

    // epilogue: O^T row = d = t*16+q4*4+r, col = q = fr -> packed ushort4
    const float rlA = 1.0f / lA;
    const float rlB = 1.0f / lB;
    u16* orowA = outb + (size_t)(b * Lc + qblkA * 64 + wave * 16 + fr) * Dc + h * 64;
    u16* orowB = outb + (size_t)(b * Lc + qblkB * 64 + wave * 16 + fr) * Dc + h * 64;
#pragma unroll
    for (int t = 0; t < 4; t++) {
        ushort4 a, o;
        a.x = f2bf(oA[t][0] * rlA);
        a.y = f2bf(oA[t][1] * rlA);
        a.z = f2bf(oA[t][2] * rlA);
        a.w = f2bf(oA[t][3] * rlA);
        *(ushort4*)(orowA + t * 16 + q4 * 4) = a;
        o.x = f2bf(oB[t][0] * rlB);
        o.y = f2bf(oB[t][1] * rlB);
        o.z = f2bf(oB[t][2] * rlB);
        o.w = f2bf(oB[t][3] * rlB);
        *(ushort4*)(orowB + t * 16 + q4 * 4) = o;
    }
}

// ---------------------------------------------------------------------------
extern "C" void kernel_launch(void* const* d_in, const int* in_sizes, int n_in,
                              void* d_out, int out_size, void* d_ws, size_t ws_size,
                              hipStream_t stream) {
    const float* x    = (const float*)d_in[0];  // [4,2048,1024] fp32
    const float* wqkv = (const float*)d_in[1];  // [3072,1024]
    const float* bqkv = (const float*)d_in[2];  // [3072]
    const float* wout = (const float*)d_in[3];  // [1024,1024]
    const float* bout = (const float*)d_in[4];  // [1024]
    float* out = (float*)d_out;                 // [4,2048,1024] fp32

    u16* qkv    = (u16*)d_ws;                       // [8192,3072] bf16 (V third unused)
    u16* attn   = qkv + (size_t)8192 * 3072;        // [8192,1024] bf16
    u16* xbf    = attn + (size_t)8192 * 1024;       // [8192,1024] bf16
    u16* wqkvbf = xbf + (size_t)8192 * 1024;        // [3072,1024] bf16
    u16* woutbf = wqkvbf + (size_t)3072 * 1024;     // [1024,1024] bf16
    u16* vT     = woutbf + (size_t)1024 * 1024;     // [1024, 8192] bf16 (V transposed)

    dim3 blk(256);
    cvt_all<<<(N_X + N_WQ + N_WO) / 1024, blk, 0, stream>>>(x, wqkv, wout, xbf);

    gemm_bt_bias<u16, true><<<dim3(3072 / 128, 8192 / 128), blk, 0, stream>>>(
        xbf, wqkvbf, bqkv, qkv, vT, 8192, 3072, 1024);
    attn_fa<<<dim3(16, 16, 4), blk, 0, stream>>>(qkv, vT, attn);
    gemm_bt_bias<float, false><<<dim3(1024 / 128, 8192 / 128), blk, 0, stream>>>(
        attn, woutbf, bout, out, nullptr, 8192, 1024, 1024);
}

// Round 8
// 267.597 us; speedup vs baseline: 1.8615x; 1.0971x over previous
//
#include <hip/hip_runtime.h>
#include <stdint.h>

#define DEV __device__ __forceinline__

typedef unsigned short u16;
typedef __bf16 bf16x8 __attribute__((ext_vector_type(8)));
typedef float f32x4 __attribute__((ext_vector_type(4)));
typedef u16 u16x8 __attribute__((ext_vector_type(8)));

#define MFMA_BF16(A, B, C) __builtin_amdgcn_mfma_f32_16x16x32_bf16(A, B, C, 0, 0, 0)
#define EXP2(x) __builtin_amdgcn_exp2f(x)

DEV u16 f2bf(float f) {
    unsigned x;
    __builtin_memcpy(&x, &f, 4);
    unsigned r = (x + 0x7fffu + ((x >> 16) & 1u)) >> 16;  // RNE
    return (u16)r;
}

DEV u16 f2bf_fast(float f) {  // round-half-up; 2 VALU ops, used in attn hot loop
    unsigned x;
    __builtin_memcpy(&x, &f, 4);
    return (u16)((x + 0x8000u) >> 16);
}

DEV void storeC(u16* p, float v) { *p = f2bf(v); }
DEV void storeC(float* p, float v) { *p = v; }

// async global->LDS, 16B per lane. LDS dest must be wave-uniform base + lane*16.
DEV void async_copy16(const u16* g, u16* l) {
    __builtin_amdgcn_global_load_lds(
        (__attribute__((address_space(1))) unsigned int*)g,
        (__attribute__((address_space(3))) unsigned int*)l, 16, 0, 0);
}

// ---------------------------------------------------------------------------
// fused fp32 -> bf16 conversion of x | wqkv | wout into one contiguous dest.
// ---------------------------------------------------------------------------
constexpr int N_X = 8192 * 1024, N_WQ = 3072 * 1024, N_WO = 1024 * 1024;

__global__ __launch_bounds__(256)
void cvt_all(const float* __restrict__ x, const float* __restrict__ wq,
             const float* __restrict__ wo, u16* __restrict__ out) {
    const int i = (blockIdx.x * 256 + threadIdx.x) * 4;
    const float* src;
    if (i < N_X) src = x + i;
    else if (i < N_X + N_WQ) src = wq + (i - N_X);
    else src = wo + (i - N_X - N_WQ);
    const float4 v = *(const float4*)src;
    ushort4 o;
    o.x = f2bf(v.x);
    o.y = f2bf(v.y);
    o.z = f2bf(v.z);
    o.w = f2bf(v.w);
    *(ushort4*)(out + i) = o;
}

// ---------------------------------------------------------------------------
// C[M,N] = A[M,K] * Bw[N,K]^T + bias[N]; A,Bw bf16, bias fp32, fp32 accum.
// 128x128 tile, BK=64 as two 32-wide panels. Grid: x = M-block, y = N-block,
// so XCD k (linear id % 8) holds A-row-tiles m≡k (mod 8) L2-resident (2 MB)
// and streams B — avoids duplicating the 16 MB A across all 8 XCDs.
// VSPLIT: cols >= 2048 (the V third of QKV) are stored TRANSPOSED into
// vT[col-2048][M] as packed ushort4, not into C.
// ---------------------------------------------------------------------------
template <typename OT, bool VSPLIT>
__global__ __launch_bounds__(256, 2)
void gemm_bt_bias(const u16* __restrict__ A, const u16* __restrict__ Bw,
                  const float* __restrict__ bias, OT* __restrict__ C,
                  u16* __restrict__ vT, int M, int N, int K) {
    __shared__ __attribute__((aligned(16))) u16 sA[2][128 * 32];
    __shared__ __attribute__((aligned(16))) u16 sB[2][128 * 32];

    const int tid  = threadIdx.x;
    const int lane = tid & 63;
    const int wave = tid >> 6;
    const int m0 = blockIdx.x * 128;   // M on x: XCD-local A reuse
    const int n0 = blockIdx.y * 128;
    const int wm = (wave & 1) * 64;
    const int wn = (wave >> 1) * 64;
    const int fr = lane & 15;
    const int q4 = lane >> 4;

    const int r0 = tid >> 2;
    const int c0 = (tid & 3) * 8;
    const u16* gA0 = A + (size_t)(m0 + r0) * K + c0;
    const u16* gA1 = A + (size_t)(m0 + 64 + r0) * K + c0;
    const u16* gB0 = Bw + (size_t)(n0 + r0) * K + c0;
    const u16* gB1 = Bw + (size_t)(n0 + 64 + r0) * K + c0;

    f32x4 acc[4][4];
#pragma unroll
    for (int i = 0; i < 4; i++)
#pragma unroll
        for (int j = 0; j < 4; j++) acc[i][j] = (f32x4){0.f, 0.f, 0.f, 0.f};

    for (int k0 = 0; k0 < K; k0 += 64) {
#pragma unroll
        for (int p = 0; p < 2; ++p) {  // two 32-wide K panels
            async_copy16(gA0 + k0 + p * 32, &sA[p][tid * 8]);
            async_copy16(gA1 + k0 + p * 32, &sA[p][2048 + tid * 8]);
            async_copy16(gB0 + k0 + p * 32, &sB[p][tid * 8]);
            async_copy16(gB1 + k0 + p * 32, &sB[p][2048 + tid * 8]);
        }
        __syncthreads();

#pragma unroll
        for (int p = 0; p < 2; ++p) {
            bf16x8 af[4], bfr[4];
#pragma unroll
            for (int i = 0; i < 4; i++)
                af[i] = *(const bf16x8*)&sA[p][(wm + i * 16 + fr) * 32 + q4 * 8];
#pragma unroll
            for (int j = 0; j < 4; j++)
                bfr[j] = *(const bf16x8*)&sB[p][(wn + j * 16 + fr) * 32 + q4 * 8];
#pragma unroll
            for (int i = 0; i < 4; i++)
#pragma unroll
                for (int j = 0; j < 4; j++)
                    acc[i][j] = MFMA_BF16(af[i], bfr[j], acc[i][j]);
        }
        __syncthreads();
    }

    // epilogue: C/D layout col=lane&15, row=quad*4+reg  [verified m89/m91]
#pragma unroll
    for (int j = 0; j < 4; j++) {
        const int col = n0 + wn + j * 16 + fr;
        const float bv = bias[col];
        if (VSPLIT && col >= 2048) {  // wave-uniform: col/16 uniform across fr
#pragma unroll
            for (int i = 0; i < 4; i++) {
                const int row = m0 + wm + i * 16 + q4 * 4;
                ushort4 o;
                o.x = f2bf(acc[i][j][0] + bv);
                o.y = f2bf(acc[i][j][1] + bv);
                o.z = f2bf(acc[i][j][2] + bv);
                o.w = f2bf(acc[i][j][3] + bv);
                *(ushort4*)&vT[(size_t)(col - 2048) * 8192 + row] = o;
            }
        } else {
#pragma unroll
            for (int i = 0; i < 4; i++) {
                const int row = m0 + wm + i * 16 + q4 * 4;
#pragma unroll
                for (int r = 0; r < 4; r++)
                    storeC(&C[(size_t)(row + r) * N + col], acc[i][j][r] + bv);
            }
        }
    }
}

// ---------------------------------------------------------------------------
// Flash attention, causal, S^T/O^T formulation, PAIRED Q-TILES, XCD-GROUPED.
// 1D grid of 1024; id -> (group g = (b,h), pair bx) such that all 16 blocks
// of one (b,h) share an XCD (dispatch round-robins XCDs by id % 8):
//   g = (id & 7) + 8*(id >> 7),  bx = (id >> 3) & 15.
// Each XCD then holds 8 groups x 512 KB K/V = 4 MB = its L2: staging hits L2.
//   S^T = K Q^T : C-layout row = key (q4*4+r), col = q (fr); softmax state is
//   per-lane scalar; P packed ushort4; O^T = V^T P^T.
// ---------------------------------------------------------------------------
constexpr int Lc = 2048, Dc = 1024;

__global__ __launch_bounds__(256, 4)
void attn_fa(const u16* __restrict__ qkv, const u16* __restrict__ vT,
             u16* __restrict__ outb) {
    __shared__ __attribute__((aligned(16))) u16 sK[64 * 72];        // [key][d]
    __shared__ __attribute__((aligned(16))) u16 sVT[64 * 72];       // [d][key]
    __shared__ __attribute__((aligned(16))) u16 sP[4][2][16 * 72];  // [wave][tile][q][key]

    const int tid  = threadIdx.x;
    const int lane = tid & 63;
    const int wave = tid >> 6;
    const int fr = lane & 15;
    const int q4 = lane >> 4;

    const int id = blockIdx.x;                  // 0..1023
    const int g  = (id & 7) + 8 * (id >> 7);    // (b,h) group, XCD = g & 7
    const int bx = (id >> 3) & 15;              // 0..15
    const int h = g & 15;
    const int b = g >> 4;
    const int qblkA = bx;                       // short tile
    const int qblkB = 31 - bx;                  // long tile

    constexpr float CEXP = 0.18033688011112042f;  // 0.125 * log2(e)

    // Q fragments (B-operand: n=fr -> q row, k=q4*8+j -> d)
    const int qrowA = qblkA * 64 + wave * 16 + fr;
    const int qrowB = qblkB * 64 + wave * 16 + fr;
    const u16* qptrA = qkv + ((size_t)(b * Lc + qrowA) * 3) * Dc + h * 64;
    const u16* qptrB = qkv + ((size_t)(b * Lc + qrowB) * 3) * Dc + h * 64;
    bf16x8 qfA[2], qfB[2];
    qfA[0] = *(const bf16x8*)(qptrA + q4 * 8);
    qfA[1] = *(const bf16x8*)(qptrA + 32 + q4 * 8);
    qfB[0] = *(const bf16x8*)(qptrB + q4 * 8);
    qfB[1] = *(const bf16x8*)(qptrB + 32 + q4 * 8);

    f32x4 oA[4], oB[4];
#pragma unroll
    for (int t = 0; t < 4; t++) {
        oA[t] = (f32x4){0.f, 0.f, 0.f, 0.f};
        oB[t] = (f32x4){0.f, 0.f, 0.f, 0.f};
    }
    float mA = -3.4e38f, lA = 0.f, mB = -3.4e38f, lB = 0.f;

    const int q_local = wave * 16 + fr;

    // staging: rr = row within half-tile, oo = 16B chunk
    const int rr = tid >> 3;
    const int oo = tid & 7;
    const u16* kg = qkv + ((size_t)(b * Lc) * 3 + 1) * Dc + h * 64 + oo * 8;  // + tok*3072
    const u16* vg = vT + (size_t)(h * 64) * 8192 + b * Lc + oo * 8;           // + d*8192 + key

    u16x8 kr[2], vr[2];
#pragma unroll
    for (int c = 0; c < 2; ++c) {
        kr[c] = *(const u16x8*)(kg + (size_t)(c * 32 + rr) * 3072);
        vr[c] = *(const u16x8*)(vg + (size_t)(c * 32 + rr) * 8192);
    }

    u16* sPA = &sP[wave][0][0];
    u16* sPB = &sP[wave][1][0];

    for (int jb = 0; jb <= qblkB; ++jb) {
        __syncthreads();  // previous iteration's LDS reads complete
#pragma unroll
        for (int c = 0; c < 2; ++c) {
            *(u16x8*)&sK[(c * 32 + rr) * 72 + oo * 8] = kr[c];
            *(u16x8*)&sVT[(c * 32 + rr) * 72 + oo * 8] = vr[c];
        }
        __syncthreads();
        if (jb < qblkB) {  // preload next tile; latency overlaps compute below
#pragma unroll
            for (int c = 0; c < 2; ++c) {
                kr[c] = *(const u16x8*)(kg + (size_t)((jb + 1) * 64 + c * 32 + rr) * 3072);
                vr[c] = *(const u16x8*)(vg + (size_t)(c * 32 + rr) * 8192 + (jb + 1) * 64);
            }
        }

        const bool doA = (jb <= qblkA);  // wave-uniform

        // S^T = K Q^T for both tiles, sharing the K-fragment reads
        f32x4 sA_[4], sB_[4];
#pragma unroll
        for (int t = 0; t < 4; t++) {
            const bf16x8 kf0 = *(const bf16x8*)&sK[(t * 16 + fr) * 72 + q4 * 8];
            const bf16x8 kf1 = *(const bf16x8*)&sK[(t * 16 + fr) * 72 + 32 + q4 * 8];
            sB_[t] = (f32x4){0.f, 0.f, 0.f, 0.f};
            sB_[t] = MFMA_BF16(kf0, qfB[0], sB_[t]);
            sB_[t] = MFMA_BF16(kf1, qfB[1], sB_[t]);
            if (doA) {
                sA_[t] = (f32x4){0.f, 0.f, 0.f, 0.f};
                sA_[t] = MFMA_BF16(kf0, qfA[0], sA_[t]);
                sA_[t] = MFMA_BF16(kf1, qfA[1], sA_[t]);
            }
        }

        // ---- tile B softmax ----
        {
            if (jb == qblkB) {
#pragma unroll
                for (int t = 0; t < 4; t++)
#pragma unroll
                    for (int r = 0; r < 4; r++)
                        if (t * 16 + q4 * 4 + r > q_local) sB_[t][r] = -1e30f;
            }
            float mx = sB_[0][0];
#pragma unroll
            for (int t = 0; t < 4; t++)
#pragma unroll
                for (int r = 0; r < 4; r++) mx = fmaxf(mx, sB_[t][r]);
            mx = fmaxf(mx, __shfl_xor(mx, 16));
            mx = fmaxf(mx, __shfl_xor(mx, 32));
            const float mnew = fmaxf(mB, mx);
            const float alpha = EXP2((mB - mnew) * CEXP);
            float sum = 0.f;
#pragma unroll
            for (int t = 0; t < 4; t++) {
#pragma unroll
                for (int r = 0; r < 4; r++) {
                    const float p = EXP2((sB_[t][r] - mnew) * CEXP);
                    sB_[t][r] = p;
                    sum += p;
                }
                ushort4 o;
                o.x = f2bf_fast(sB_[t][0]);
                o.y = f2bf_fast(sB_[t][1]);
                o.z = f2bf_fast(sB_[t][2]);
                o.w = f2bf_fast(sB_[t][3]);
                *(ushort4*)&sPB[fr * 72 + t * 16 + q4 * 4] = o;
            }
            sum += __shfl_xor(sum, 16);
            sum += __shfl_xor(sum, 32);
            lB = alpha * lB + sum;
            mB = mnew;
#pragma unroll
            for (int t = 0; t < 4; t++)
#pragma unroll
                for (int r = 0; r < 4; r++) oB[t][r] *= alpha;
        }

        // ---- tile A softmax ----
        if (doA) {
            if (jb == qblkA) {
#pragma unroll
                for (int t = 0; t < 4; t++)
#pragma unroll
                    for (int r = 0; r < 4; r++)
                        if (t * 16 + q4 * 4 + r > q_local) sA_[t][r] = -1e30f;
            }
            float mx = sA_[0][0];
#pragma unroll
            for (int t = 0; t < 4; t++)
#pragma unroll
                for (int r = 0; r < 4; r++) mx = fmaxf(mx, sA_[t][r]);
            mx = fmaxf(mx, __shfl_xor(mx, 16));
            mx = fmaxf(mx, __shfl_xor(mx, 32));
            const float mnew = fmaxf(mA, mx);
            const float alpha = EXP2((mA - mnew) * CEXP);
            float sum = 0.f;
#pragma unroll
            for (int t = 0; t < 4; t++) {
#pragma unroll
                for (int r = 0; r < 4; r++) {
                    const float p = EXP2((sA_[t][r] - mnew) * CEXP);
                    sA_[t][r] = p;
                    sum += p;
                }
                ushort4 o;
                o.x = f2bf_fast(sA_[t][0]);
                o.y = f2bf_fast(sA_[t][1]);
                o.z = f2bf_fast(sA_[t][2]);
                o.w = f2bf_fast(sA_[t][3]);
                *(ushort4*)&sPA[fr * 72 + t * 16 + q4 * 4] = o;
            }
            sum += __shfl_xor(sum, 16);
            sum += __shfl_xor(sum, 32);
            lA = alpha * lA + sum;
            mA = mnew;
#pragma unroll
            for (int t = 0; t < 4; t++)
#pragma unroll
                for (int r = 0; r < 4; r++) oA[t][r] *= alpha;
        }

        // O^T += V^T P^T, sharing the V-fragment reads (wave-local sP; DS in-order)
#pragma unroll
        for (int ks = 0; ks < 2; ++ks) {
            const bf16x8 pfB = *(const bf16x8*)&sPB[fr * 72 + ks * 32 + q4 * 8];
            bf16x8 pfA;
            if (doA) pfA = *(const bf16x8*)&sPA[fr * 72 + ks * 32 + q4 * 8];
#pragma unroll
            for (int t = 0; t < 4; t++) {
                const bf16x8 vf = *(const bf16x8*)&sVT[(t * 16 + fr) * 72 + ks * 32 + q4 * 8];
                oB[t] = MFMA_BF16(vf, pfB, oB[t]);
                if (doA) oA[t] = MFMA_BF16(vf, pfA, oA[t]);
            }
        }
    }

    // epilogue: O^T row = d = t*16+q4*4+r, col = q = fr -> packed ushort4
    const float rlA = 1.0f / lA;
    const float rlB = 1.0f / lB;
    u16* orowA = outb + (size_t)(b * Lc + qblkA * 64 + wave * 16 + fr) * Dc + h * 64;
    u16* orowB = outb + (size_t)(b * Lc + qblkB * 64 + wave * 16 + fr) * Dc + h * 64;
#pragma unroll
    for (int t = 0; t < 4; t++) {
        ushort4 a, o;
        a.x = f2bf(oA[t][0] * rlA);
        a.y = f2bf(oA[t][1] * rlA);
        a.z = f2bf(oA[t][2] * rlA);
        a.w = f2bf(oA[t][3] * rlA);
        *(ushort4*)(orowA + t * 16 + q4 * 4) = a;
        o.x = f2bf(oB[t][0] * rlB);
        o.y = f2bf(oB[t][1] * rlB);
        o.z = f2bf(oB[t][2] * rlB);
        o.w = f2bf(oB[t][3] * rlB);
        *(ushort4*)(orowB + t * 16 + q4 * 4) = o;
    }
}

// ---------------------------------------------------------------------------
extern "C" void kernel_launch(void* const* d_in, const int* in_sizes, int n_in,
                              void* d_out, int out_size, void* d_ws, size_t ws_size,
                              hipStream_t stream) {
    const float* x    = (const float*)d_in[0];  // [4,2048,1024] fp32
    const float* wqkv = (const float*)d_in[1];  // [3072,1024]
    const float* bqkv = (const float*)d_in[2];  // [3072]
    const float* wout = (const float*)d_in[3];  // [1024,1024]
    const float* bout = (const float*)d_in[4];  // [1024]
    float* out = (float*)d_out;                 // [4,2048,1024] fp32

    u16* qkv    = (u16*)d_ws;                       // [8192,3072] bf16 (V third unused)
    u16* attn   = qkv + (size_t)8192 * 3072;        // [8192,1024] bf16
    u16* xbf    = attn + (size_t)8192 * 1024;       // [8192,1024] bf16
    u16* wqkvbf = xbf + (size_t)8192 * 1024;        // [3072,1024] bf16
    u16* woutbf = wqkvbf + (size_t)3072 * 1024;     // [1024,1024] bf16
    u16* vT     = woutbf + (size_t)1024 * 1024;     // [1024, 8192] bf16 (V transposed)

    dim3 blk(256);
    cvt_all<<<(N_X + N_WQ + N_WO) / 1024, blk, 0, stream>>>(x, wqkv, wout, xbf);

    gemm_bt_bias<u16, true><<<dim3(8192 / 128, 3072 / 128), blk, 0, stream>>>(
        xbf, wqkvbf, bqkv, qkv, vT, 8192, 3072, 1024);
    attn_fa<<<dim3(1024), blk, 0, stream>>>(qkv, vT, attn);
    gemm_bt_bias<float, false><<<dim3(8192 / 128, 1024 / 128), blk, 0, stream>>>(
        attn, woutbf, bout, out, nullptr, 8192, 1024, 1024);
}